// Round 1
// baseline (853.220 us; speedup 1.0000x reference)
//
#include <hip/hip_runtime.h>
#include <math.h>

#define NNPTS 131072          // B*N*K
#define NQ    8192            // B*N

// ---------------- GEMM tile helper ----------------
// Block 256 threads: tx=tid&31 -> rows r=tx*4..+3 (128 rows); ty=tid>>5 -> cols p=ty*8..+7 (64 cols)
// WT: global [128][128], WT[i][c] = W[c][i] (transposed)
// Xs: LDS [64][132], Xs[p][i] = X[i][p]
// acc[rr][pp] += sum_i W[r][i] * X[i][p]
__device__ __forceinline__ void gemm_tile(const float* __restrict__ WT,
                                          float (* __restrict__ Xs)[132],
                                          float acc[4][8], float* Ws,
                                          int tx, int ty)
{
  #pragma unroll 1
  for (int i0 = 0; i0 < 128; i0 += 8) {
    __syncthreads();
    for (int u = threadIdx.x; u < 8*128; u += 256) Ws[u] = WT[i0*128 + u];
    __syncthreads();
    #pragma unroll
    for (int i = 0; i < 8; i += 4) {
      float4 x4[8];
      #pragma unroll
      for (int pp = 0; pp < 8; ++pp)
        x4[pp] = *(const float4*)&Xs[ty*8+pp][i0+i];
      #pragma unroll
      for (int ii = 0; ii < 4; ++ii) {
        float4 w = *(const float4*)&Ws[(i+ii)*128 + tx*4];
        float wv0=w.x, wv1=w.y, wv2=w.z, wv3=w.w;
        #pragma unroll
        for (int pp = 0; pp < 8; ++pp) {
          float xv = ((const float*)&x4[pp])[ii];
          acc[0][pp] = fmaf(wv0, xv, acc[0][pp]);
          acc[1][pp] = fmaf(wv1, xv, acc[1][pp]);
          acc[2][pp] = fmaf(wv2, xv, acc[2][pp]);
          acc[3][pp] = fmaf(wv3, xv, acc[3][pp]);
        }
      }
    }
  }
  __syncthreads();
}

// ---------------- transpose features [B][C][N] -> featT [B][N][C] ----------------
__global__ __launch_bounds__(256) void transpose_feat(const float* __restrict__ f,
                                                      float* __restrict__ ft)
{
  int i = blockIdx.x*256 + threadIdx.x;     // enumerates [b][n][c], c fastest
  int c = i & 127, n = (i >> 7) & 4095, b = i >> 19;
  ft[i] = f[(((size_t)b << 7) + c) * 4096 + n];
}

// ---------------- weight prep: transposes + fused products ----------------
__global__ __launch_bounds__(128) void prep_weights(
    const float* __restrict__ wphi, const float* __restrict__ wpsi,
    const float* __restrict__ walpha,
    const float* __restrict__ wg1, const float* __restrict__ wg2,
    const float* __restrict__ bg1, const float* __restrict__ bg2,
    const float* __restrict__ wt1, const float* __restrict__ bt1,
    const float* __restrict__ wt2, const float* __restrict__ bt2,
    float* __restrict__ WphiT, float* __restrict__ WpsiT, float* __restrict__ WalphaT,
    float* __restrict__ WfusT, float* __restrict__ c0,
    float* __restrict__ Wc, float* __restrict__ bc)
{
  int i = blockIdx.x, c = threadIdx.x;
  WphiT[i*128+c]   = wphi[c*128+i];
  WpsiT[i*128+c]   = wpsi[c*128+i];
  WalphaT[i*128+c] = walpha[c*128+i];
  float s = 0.f;
  for (int t = 0; t < 128; ++t) s = fmaf(wg2[c*128+t], wg1[t*128+i], s);
  WfusT[i*128+c] = s;
  if (i == 0) {
    float s0 = bg2[c];
    for (int t = 0; t < 128; ++t) s0 = fmaf(wg2[c*128+t], bg1[t], s0);
    c0[c] = s0;
    for (int j = 0; j < 3; ++j) {
      float a = 0.f;
      for (int t = 0; t < 128; ++t) a = fmaf(wt2[c*128+t], wt1[t*3+j], a);
      Wc[c*3+j] = a;
    }
    float bb = bt2[c];
    for (int t = 0; t < 128; ++t) bb = fmaf(wt2[c*128+t], bt1[t], bb);
    bc[c] = bb;
  }
}

// ---------------- KNN: block per query, 16 argmax rounds, stable tie-break ----------------
__global__ __launch_bounds__(256) void knn_kernel(const float* __restrict__ xyz,
                                                  int* __restrict__ idxOut)
{
  __shared__ float dist[4096];
  __shared__ float rv[256];
  __shared__ int   ri[256];
  int bid = blockIdx.x;
  int b = bid >> 12, n = bid & 4095;
  const float* X = xyz + (size_t)b * 3 * 4096;
  float qx = X[n], qy = X[4096+n], qz = X[8192+n];
  // xx_n: products rounded, then summed (numpy: (x*x + y*y) + z*z)
  float xxq = __fadd_rn(__fadd_rn(__fmul_rn(qx,qx), __fmul_rn(qy,qy)), __fmul_rn(qz,qz));
  for (int m = threadIdx.x; m < 4096; m += 256) {
    float mx = X[m], my = X[4096+m], mz = X[8192+m];
    float xxm = __fadd_rn(__fadd_rn(__fmul_rn(mx,mx), __fmul_rn(my,my)), __fmul_rn(mz,mz));
    float dot = __fadd_rn(__fadd_rn(__fmul_rn(qx,mx), __fmul_rn(qy,my)), __fmul_rn(qz,mz));
    float inner = __fmul_rn(-2.0f, dot);
    // dist[b,n,m] = ((-xx_m) - inner) - xx_n  (exact broadcast order of the reference)
    dist[m] = __fsub_rn(__fsub_rn(-xxm, inner), xxq);
  }
  __syncthreads();
  for (int r = 0; r < 16; ++r) {
    float bv = -INFINITY; int bi = 0x7fffffff;
    for (int m = threadIdx.x; m < 4096; m += 256) {
      float v = dist[m];
      if (v > bv || (v == bv && m < bi)) { bv = v; bi = m; }
    }
    rv[threadIdx.x] = bv; ri[threadIdx.x] = bi;
    __syncthreads();
    for (int s = 128; s > 0; s >>= 1) {
      if (threadIdx.x < s) {
        float ov = rv[threadIdx.x+s]; int oi = ri[threadIdx.x+s];
        float cv = rv[threadIdx.x];   int ci = ri[threadIdx.x];
        if (ov > cv || (ov == cv && oi < ci)) { rv[threadIdx.x] = ov; ri[threadIdx.x] = oi; }
      }
      __syncthreads();
    }
    if (threadIdx.x == 0) {
      idxOut[(size_t)bid*16 + r] = ri[0];
      dist[ri[0]] = -INFINITY;
    }
    __syncthreads();
  }
}

// ---------------- phi GEMM: linxiT[pt][c] = Wphi @ featT[pt] + bphi ----------------
__global__ __launch_bounds__(256) void phi_gemm(const float* __restrict__ featT,
                                                const float* __restrict__ WphiT,
                                                const float* __restrict__ bphi,
                                                float* __restrict__ linxiT)
{
  __shared__ float Xs[64][132];
  __shared__ float Ws[8*128];
  int tid = threadIdx.x, tx = tid & 31, ty = tid >> 5;
  int g0 = blockIdx.x * 64;
  for (int u = tid; u < 64*32; u += 256) {
    int p = u >> 5, c4 = (u & 31) << 2;
    *(float4*)&Xs[p][c4] = *(const float4*)&featT[(size_t)(g0+p)*128 + c4];
  }
  float acc[4][8];
  #pragma unroll
  for (int rr = 0; rr < 4; ++rr)
    #pragma unroll
    for (int pp = 0; pp < 8; ++pp) acc[rr][pp] = 0.f;
  gemm_tile(WphiT, Xs, acc, Ws, tx, ty);
  float4 bv = *(const float4*)&bphi[tx*4];
  float bb[4] = {bv.x, bv.y, bv.z, bv.w};
  #pragma unroll
  for (int pp = 0; pp < 8; ++pp) {
    float4 v = make_float4(acc[0][pp]+bb[0], acc[1][pp]+bb[1], acc[2][pp]+bb[2], acc[3][pp]+bb[3]);
    *(float4*)&linxiT[(size_t)(g0 + ty*8 + pp)*128 + tx*4] = v;
  }
}

// ---------------- pos second moments (double) ----------------
__global__ __launch_bounds__(256) void pos_stats(const float* __restrict__ xyz,
                                                 const int* __restrict__ idx,
                                                 double* __restrict__ st)
{
  __shared__ double rd[256];
  int qg = blockIdx.x*256 + threadIdx.x;   // 0..8191
  int b = qg >> 12, n = qg & 4095;
  const float* X = xyz + (size_t)b * 3 * 4096;
  float qx = X[n], qy = X[4096+n], qz = X[8192+n];
  double l[9] = {0,0,0,0,0,0,0,0,0};
  for (int kk = 0; kk < 16; ++kk) {
    int nb = idx[(size_t)qg*16 + kk];
    float px = qx - X[nb], py = qy - X[4096+nb], pz = qz - X[8192+nb];
    l[0] += px; l[1] += py; l[2] += pz;
    l[3] += (double)px*px; l[4] += (double)px*py; l[5] += (double)px*pz;
    l[6] += (double)py*py; l[7] += (double)py*pz; l[8] += (double)pz*pz;
  }
  for (int j = 0; j < 9; ++j) {
    __syncthreads();
    rd[threadIdx.x] = l[j];
    __syncthreads();
    for (int s = 128; s > 0; s >>= 1) {
      if (threadIdx.x < s) rd[threadIdx.x] += rd[threadIdx.x + s];
      __syncthreads();
    }
    if (threadIdx.x == 0) atomicAdd(&st[j], rd[0]);
  }
}

// ---------------- fold theta BN analytically: delta = relu(Wd.pos + bd) ----------------
__global__ __launch_bounds__(128) void theta_fold(const double* __restrict__ st,
                                                  const float* __restrict__ Wc,
                                                  const float* __restrict__ bc,
                                                  const float* __restrict__ g,
                                                  const float* __restrict__ be,
                                                  float* __restrict__ WdT,
                                                  float* __restrict__ bd)
{
  int c = threadIdx.x;
  const double cnt = (double)NNPTS;
  double m0 = st[0]/cnt, m1 = st[1]/cnt, m2 = st[2]/cnt;
  double Pxx = st[3]/cnt, Pxy = st[4]/cnt, Pxz = st[5]/cnt;
  double Pyy = st[6]/cnt, Pyz = st[7]/cnt, Pzz = st[8]/cnt;
  double w0 = Wc[c*3], w1 = Wc[c*3+1], w2 = Wc[c*3+2], bb = bc[c];
  double wm = w0*m0 + w1*m1 + w2*m2;
  double mu = wm + bb;
  double quad = w0*(Pxx*w0 + Pxy*w1 + Pxz*w2)
              + w1*(Pxy*w0 + Pyy*w1 + Pyz*w2)
              + w2*(Pxz*w0 + Pyz*w1 + Pzz*w2);
  double Ex2 = quad + 2.0*bb*wm + bb*bb;
  double var = Ex2 - mu*mu;
  double s = (double)g[c] / sqrt(var + 1e-5);
  double t = (double)be[c] - s*mu;
  WdT[0*128+c] = (float)(s*w0);
  WdT[1*128+c] = (float)(s*w1);
  WdT[2*128+c] = (float)(s*w2);
  bd[c] = (float)(s*bb + t);
}

// ---------------- gamma BN stats reduce (double) ----------------
__global__ __launch_bounds__(128) void gamma_reduce(const float* __restrict__ gs,
                                                    const float* __restrict__ gq,
                                                    const float* __restrict__ g,
                                                    const float* __restrict__ be,
                                                    float* __restrict__ s2,
                                                    float* __restrict__ t2v)
{
  int c = threadIdx.x;
  double S = 0.0, Q = 0.0;
  for (int bk = 0; bk < 2048; ++bk) {
    S += gs[(size_t)bk*128 + c];
    Q += gq[(size_t)bk*128 + c];
  }
  const double cnt = (double)NNPTS;
  double m = S/cnt, v = Q/cnt - m*m;
  double s = (double)g[c] / sqrt(v + 1e-5);
  s2[c]  = (float)s;
  t2v[c] = (float)((double)be[c] - s*m);
}

// ---------------- main pass: PASS=1 stats, PASS=2 final ----------------
template<int PASS>
__global__ __launch_bounds__(256) void pass_kernel(
    const float* __restrict__ featT, const float* __restrict__ linxiT,
    const int* __restrict__ idx, const float* __restrict__ xyz,
    const float* __restrict__ WpsiT, const float* __restrict__ bpsi,
    const float* __restrict__ WfusT, const float* __restrict__ c0,
    const float* __restrict__ WdT, const float* __restrict__ bd,
    const float* __restrict__ WalphaT, const float* __restrict__ balpha,
    const float* __restrict__ s2, const float* __restrict__ t2v,
    float* __restrict__ gpart_s, float* __restrict__ gpart_q,
    float* __restrict__ out)
{
  __shared__ float Xs[64][132];
  __shared__ float Rs[64][132];
  __shared__ float Ws[8*128];
  __shared__ float Lx[4][128];
  __shared__ float posS[3][64];
  __shared__ int   pidx[64];
  __shared__ float redS[128];
  __shared__ float redQ[128];

  int tid = threadIdx.x, tx = tid & 31, ty = tid >> 5;
  int q0 = blockIdx.x * 4;          // global query (b*4096+n), 4 per block
  int b  = q0 >> 12;
  int n0 = q0 & 4095;
  const float* X = xyz + (size_t)b * 3 * 4096;

  if (tid < 64) {
    int q = tid >> 4;
    int nb = idx[(size_t)(q0 + q)*16 + (tid & 15)];
    pidx[tid] = nb;
    int nq = n0 + q;
    posS[0][tid] = X[nq]      - X[nb];
    posS[1][tid] = X[4096+nq] - X[4096+nb];
    posS[2][tid] = X[8192+nq] - X[8192+nb];
  }
  if (PASS == 1 && tid < 128) { redS[tid] = 0.f; redQ[tid] = 0.f; }
  for (int u = tid; u < 4*128; u += 256) {
    int q = u >> 7, c = u & 127;
    Lx[q][c] = linxiT[(size_t)(q0 + q)*128 + c];
  }
  __syncthreads();
  for (int u = tid; u < 64*32; u += 256) {
    int p = u >> 5, c4 = (u & 31) << 2;
    *(float4*)&Xs[p][c4] = *(const float4*)&featT[((size_t)(b << 12) + pidx[p])*128 + c4];
  }

  int r0 = tx * 4;
  float4 t4;
  t4 = *(const float4*)&WdT[0*128 + r0]; float wd0[4] = {t4.x,t4.y,t4.z,t4.w};
  t4 = *(const float4*)&WdT[1*128 + r0]; float wd1[4] = {t4.x,t4.y,t4.z,t4.w};
  t4 = *(const float4*)&WdT[2*128 + r0]; float wd2[4] = {t4.x,t4.y,t4.z,t4.w};
  t4 = *(const float4*)&bd[r0];          float bdv[4] = {t4.x,t4.y,t4.z,t4.w};
  t4 = *(const float4*)&bpsi[r0];        float bps[4] = {t4.x,t4.y,t4.z,t4.w};
  t4 = *(const float4*)&c0[r0];          float c0v[4] = {t4.x,t4.y,t4.z,t4.w};

  float acc[4][8];
  #pragma unroll
  for (int rr = 0; rr < 4; ++rr)
    #pragma unroll
    for (int pp = 0; pp < 8; ++pp) acc[rr][pp] = 0.f;
  gemm_tile(WpsiT, Xs, acc, Ws, tx, ty);   // lin_xj (no bias yet)

  int qq = ty >> 1;                        // this thread's query (fixed: its 8 cols span one q)
  float4 lxv = *(const float4*)&Lx[qq][r0];
  float lx[4] = {lxv.x, lxv.y, lxv.z, lxv.w};

  #pragma unroll
  for (int pp = 0; pp < 8; ++pp) {
    int p = ty*8 + pp;
    float p0 = posS[0][p], p1 = posS[1][p], p2 = posS[2][p];
    float4 v; float* vv = (float*)&v;
    #pragma unroll
    for (int rr = 0; rr < 4; ++rr) {
      float d = fmaf(wd2[rr], p2, fmaf(wd1[rr], p1, fmaf(wd0[rr], p0, bdv[rr])));
      d = fmaxf(d, 0.f);
      vv[rr] = lx[rr] - (acc[rr][pp] + bps[rr]) + d;   // rel0
    }
    *(float4*)&Rs[p][r0] = v;
  }
  __syncthreads();

  #pragma unroll
  for (int rr = 0; rr < 4; ++rr)
    #pragma unroll
    for (int pp = 0; pp < 8; ++pp) acc[rr][pp] = 0.f;
  gemm_tile(WfusT, Rs, acc, Ws, tx, ty);   // g2 - c0

  if (PASS == 1) {
    #pragma unroll
    for (int rr = 0; rr < 4; ++rr) {
      float s = 0.f, qs = 0.f;
      #pragma unroll
      for (int pp = 0; pp < 8; ++pp) {
        float gg = acc[rr][pp] + c0v[rr];
        s += gg; qs = fmaf(gg, gg, qs);
      }
      atomicAdd(&redS[r0+rr], s);
      atomicAdd(&redQ[r0+rr], qs);
    }
    __syncthreads();
    if (tid < 128) {
      gpart_s[(size_t)blockIdx.x*128 + tid] = redS[tid];
      gpart_q[(size_t)blockIdx.x*128 + tid] = redQ[tid];
    }
    return;
  }

  // ---- PASS 2 ----
  float4 s4 = *(const float4*)&s2[r0];  float sv[4] = {s4.x,s4.y,s4.z,s4.w};
  float4 v4 = *(const float4*)&t2v[r0]; float tv[4] = {v4.x,v4.y,v4.z,v4.w};
  float rel[4][8];
  #pragma unroll
  for (int rr = 0; rr < 4; ++rr)
    #pragma unroll
    for (int pp = 0; pp < 8; ++pp) {
      float gg = acc[rr][pp] + c0v[rr];
      rel[rr][pp] = fmaxf(fmaf(sv[rr], gg, tv[rr]), 0.f);
    }
  // Rs reads finished at gemm_tile's trailing barrier -> safe to overwrite
  #pragma unroll
  for (int pp = 0; pp < 8; ++pp) {
    int p = ty*8 + pp;
    *(float4*)&Rs[p][r0] = make_float4(rel[0][pp], rel[1][pp], rel[2][pp], rel[3][pp]);
  }

  #pragma unroll
  for (int rr = 0; rr < 4; ++rr)
    #pragma unroll
    for (int pp = 0; pp < 8; ++pp) acc[rr][pp] = 0.f;
  gemm_tile(WalphaT, Xs, acc, Ws, tx, ty); // alpha conv
  float4 ba4 = *(const float4*)&balpha[r0]; float bav[4] = {ba4.x,ba4.y,ba4.z,ba4.w};
  // Xs reads finished -> overwrite with feats
  #pragma unroll
  for (int pp = 0; pp < 8; ++pp) {
    int p = ty*8 + pp;
    float p0 = posS[0][p], p1 = posS[1][p], p2 = posS[2][p];
    float4 v; float* vv = (float*)&v;
    #pragma unroll
    for (int rr = 0; rr < 4; ++rr) {
      float d = fmaf(wd2[rr], p2, fmaf(wd1[rr], p1, fmaf(wd0[rr], p0, bdv[rr])));
      d = fmaxf(d, 0.f);
      vv[rr] = acc[rr][pp] + bav[rr] + d;
    }
    *(float4*)&Xs[p][r0] = v;
  }
  __syncthreads();

  // softmax over K + weighted sum
  for (int t = tid; t < 512; t += 256) {
    int c = t & 127, q = t >> 7;
    int pb = q * 16;
    float m = -INFINITY;
    #pragma unroll
    for (int kk = 0; kk < 16; ++kk) m = fmaxf(m, Rs[pb+kk][c]);
    float ssum = 0.f, osum = 0.f;
    #pragma unroll
    for (int kk = 0; kk < 16; ++kk) {
      float e = expf(Rs[pb+kk][c] - m);
      ssum += e;
      osum = fmaf(e, Xs[pb+kk][c], osum);
    }
    out[(((size_t)b*128 + c) << 12) + (n0 + q)] = osum / ssum;
  }
}

extern "C" void kernel_launch(void* const* d_in, const int* in_sizes, int n_in,
                              void* d_out, int out_size, void* d_ws, size_t ws_size,
                              hipStream_t stream)
{
  const float* xyz      = (const float*)d_in[0];
  const float* features = (const float*)d_in[1];
  const float* wt1      = (const float*)d_in[2];
  const float* bt1      = (const float*)d_in[3];
  const float* wt2      = (const float*)d_in[4];
  const float* bt2      = (const float*)d_in[5];
  const float* gth      = (const float*)d_in[6];
  const float* bth      = (const float*)d_in[7];
  const float* wphi     = (const float*)d_in[8];
  const float* bphi     = (const float*)d_in[9];
  const float* wpsi     = (const float*)d_in[10];
  const float* bpsi     = (const float*)d_in[11];
  const float* walpha   = (const float*)d_in[12];
  const float* balpha   = (const float*)d_in[13];
  const float* wg1      = (const float*)d_in[14];
  const float* bg1      = (const float*)d_in[15];
  const float* wg2      = (const float*)d_in[16];
  const float* bg2      = (const float*)d_in[17];
  const float* gga      = (const float*)d_in[18];
  const float* bga      = (const float*)d_in[19];

  char* w = (char*)d_ws;
  size_t off = 0;
  auto take = [&](size_t bytes) -> void* {
    void* p = w + off;
    off = (off + bytes + 255) & ~(size_t)255;
    return p;
  };
  int*    idxW    = (int*)   take((size_t)NQ*16*4);
  float*  featT   = (float*) take((size_t)NQ*128*4);
  float*  linxiT  = (float*) take((size_t)NQ*128*4);
  float*  WphiT   = (float*) take(65536);
  float*  WpsiT   = (float*) take(65536);
  float*  WalphaT = (float*) take(65536);
  float*  WfusT   = (float*) take(65536);
  float*  c0      = (float*) take(512);
  float*  Wc      = (float*) take(1536);
  float*  bc      = (float*) take(512);
  float*  WdT     = (float*) take(1536);
  float*  bd      = (float*) take(512);
  double* st      = (double*)take(96);
  float*  gs      = (float*) take((size_t)2048*128*4);
  float*  gq      = (float*) take((size_t)2048*128*4);
  float*  s2      = (float*) take(512);
  float*  t2v     = (float*) take(512);
  float*  out     = (float*)d_out;

  hipMemsetAsync(st, 0, 96, stream);
  transpose_feat<<<4096, 256, 0, stream>>>(features, featT);
  prep_weights<<<128, 128, 0, stream>>>(wphi, wpsi, walpha, wg1, wg2, bg1, bg2,
                                        wt1, bt1, wt2, bt2,
                                        WphiT, WpsiT, WalphaT, WfusT, c0, Wc, bc);
  knn_kernel<<<8192, 256, 0, stream>>>(xyz, idxW);
  phi_gemm<<<128, 256, 0, stream>>>(featT, WphiT, bphi, linxiT);
  pos_stats<<<32, 256, 0, stream>>>(xyz, idxW, st);
  theta_fold<<<1, 128, 0, stream>>>(st, Wc, bc, gth, bth, WdT, bd);
  pass_kernel<1><<<2048, 256, 0, stream>>>(featT, linxiT, idxW, xyz,
      WpsiT, bpsi, WfusT, c0, WdT, bd, WalphaT, balpha, s2, t2v, gs, gq, out);
  gamma_reduce<<<1, 128, 0, stream>>>(gs, gq, gga, bga, s2, t2v);
  pass_kernel<2><<<2048, 256, 0, stream>>>(featT, linxiT, idxW, xyz,
      WpsiT, bpsi, WfusT, c0, WdT, bd, WalphaT, balpha, s2, t2v, gs, gq, out);
}

// Round 2
// 453.015 us; speedup vs baseline: 1.8834x; 1.8834x over previous
//
#include <hip/hip_runtime.h>
#include <math.h>

typedef __attribute__((ext_vector_type(8))) short short8;
typedef __attribute__((ext_vector_type(4))) float f32x4;
typedef unsigned short u16;

#define NNPTS 131072          // B*N*K
#define NQ    8192            // B*N

__device__ __forceinline__ u16 f2bf(float f) {
  unsigned u = __float_as_uint(f);
  u = u + 0x7fffu + ((u >> 16) & 1u);
  return (u16)(u >> 16);
}

// ---------------- transpose features [B][C][N] -> featB bf16 [B][N][C] ----------------
__global__ __launch_bounds__(256) void transpose_feat(const float* __restrict__ f,
                                                      u16* __restrict__ featB)
{
  __shared__ float T[64][65];
  int tx = threadIdx.x & 63, tg = threadIdx.x >> 6;
  int n0 = blockIdx.x * 64, c0 = blockIdx.y * 64, b = blockIdx.z;
  const float* src = f + ((size_t)b * 128 + c0) * 4096 + n0;
  #pragma unroll
  for (int it = 0; it < 16; ++it) {
    int cl = tg + it * 4;
    T[cl][tx] = src[(size_t)cl * 4096 + tx];
  }
  __syncthreads();
  u16* dst = featB + ((size_t)b * 4096 + n0) * 128 + c0;
  #pragma unroll
  for (int it = 0; it < 16; ++it) {
    int nl = tg + it * 4;
    dst[(size_t)nl * 128 + tx] = f2bf(T[tx][nl]);
  }
}

// ---------------- weight prep: bf16 casts + fused products ----------------
__global__ __launch_bounds__(128) void prep_weights(
    const float* __restrict__ wphi, const float* __restrict__ wpsi,
    const float* __restrict__ walpha,
    const float* __restrict__ wg1, const float* __restrict__ wg2,
    const float* __restrict__ bg1, const float* __restrict__ bg2,
    const float* __restrict__ wt1, const float* __restrict__ bt1,
    const float* __restrict__ wt2, const float* __restrict__ bt2,
    u16* __restrict__ WphiB, u16* __restrict__ WpsiB, u16* __restrict__ WalphaB,
    u16* __restrict__ WfusB, float* __restrict__ c0,
    float* __restrict__ Wc, float* __restrict__ bc)
{
  int cc = blockIdx.x, i = threadIdx.x;
  WphiB[cc*128+i]   = f2bf(wphi[cc*128+i]);
  WpsiB[cc*128+i]   = f2bf(wpsi[cc*128+i]);
  WalphaB[cc*128+i] = f2bf(walpha[cc*128+i]);
  float s = 0.f;
  for (int t = 0; t < 128; ++t) s = fmaf(wg2[cc*128+t], wg1[t*128+i], s);
  WfusB[cc*128+i] = f2bf(s);
  if (i == 0) {
    float s0 = bg2[cc];
    for (int t = 0; t < 128; ++t) s0 = fmaf(wg2[cc*128+t], bg1[t], s0);
    c0[cc] = s0;
    for (int j = 0; j < 3; ++j) {
      float a = 0.f;
      for (int t = 0; t < 128; ++t) a = fmaf(wt2[cc*128+t], wt1[t*3+j], a);
      Wc[cc*3+j] = a;
    }
    float bb = bt2[cc];
    for (int t = 0; t < 128; ++t) bb = fmaf(wt2[cc*128+t], bt1[t], bb);
    bc[cc] = bb;
  }
}

// ---------------- KNN: cached chunk maxima, wave-shfl reduce, exact tie-break ----------------
__global__ __launch_bounds__(256) void knn_kernel(const float* __restrict__ xyz,
                                                  int* __restrict__ idxOut)
{
  __shared__ float dist[4096];
  __shared__ float cmax[256];
  __shared__ int   cidx[256];
  __shared__ float wv[4];
  __shared__ int   wi[4];
  int tid = threadIdx.x;
  int bid = blockIdx.x, b = bid >> 12, n = bid & 4095;
  const float* X = xyz + (size_t)b * 12288;
  float qx = X[n], qy = X[4096+n], qz = X[8192+n];
  float xxq = __fadd_rn(__fadd_rn(__fmul_rn(qx,qx), __fmul_rn(qy,qy)), __fmul_rn(qz,qz));
  float bv = -INFINITY; int bi = 0x7fffffff;
  for (int m = tid; m < 4096; m += 256) {
    float mx = X[m], my = X[4096+m], mz = X[8192+m];
    float xxm = __fadd_rn(__fadd_rn(__fmul_rn(mx,mx), __fmul_rn(my,my)), __fmul_rn(mz,mz));
    float dot = __fadd_rn(__fadd_rn(__fmul_rn(qx,mx), __fmul_rn(qy,my)), __fmul_rn(qz,mz));
    float inner = __fmul_rn(-2.0f, dot);
    float dv = __fsub_rn(__fsub_rn(-xxm, inner), xxq);   // exact ref order
    dist[m] = dv;
    if (dv > bv || (dv == bv && m < bi)) { bv = dv; bi = m; }
  }
  cmax[tid] = bv; cidx[tid] = bi;
  __syncthreads();
  for (int r = 0; r < 16; ++r) {
    float v = cmax[tid]; int i = cidx[tid];
    #pragma unroll
    for (int d = 1; d < 64; d <<= 1) {
      float ov = __shfl_xor(v, d); int oi = __shfl_xor(i, d);
      if (ov > v || (ov == v && oi < i)) { v = ov; i = oi; }
    }
    if ((tid & 63) == 0) { wv[tid >> 6] = v; wi[tid >> 6] = i; }
    __syncthreads();
    float gv = wv[0]; int gi = wi[0];
    #pragma unroll
    for (int j = 1; j < 4; ++j) {
      float ov = wv[j]; int oi = wi[j];
      if (ov > gv || (ov == gv && oi < gi)) { gv = ov; gi = oi; }
    }
    if (tid == (gi & 255)) {
      idxOut[(size_t)bid*16 + r] = gi;
      dist[gi] = -INFINITY;
      float nb = -INFINITY; int ni = 0x7fffffff;
      for (int m = tid; m < 4096; m += 256) {
        float dv = dist[m];
        if (dv > nb || (dv == nb && m < ni)) { nb = dv; ni = m; }
      }
      cmax[tid] = nb; cidx[tid] = ni;
    }
    __syncthreads();
  }
}

// ---------------- MFMA helpers ----------------
__device__ __forceinline__ void zero_acc(f32x4 a[2][4]) {
  #pragma unroll
  for (int mt = 0; mt < 2; ++mt)
    #pragma unroll
    for (int nt = 0; nt < 4; ++nt)
      a[mt][nt] = (f32x4){0.f, 0.f, 0.f, 0.f};
}

__device__ __forceinline__ void load_af(const u16* __restrict__ WB, int m0, int row, int g,
                                        short8 a[2][4]) {
  #pragma unroll
  for (int mt = 0; mt < 2; ++mt)
    #pragma unroll
    for (int kc = 0; kc < 4; ++kc)
      a[mt][kc] = *(const short8*)&WB[(size_t)(m0 + mt*16 + row)*128 + kc*32 + g*8];
}

__device__ __forceinline__ void gemm64(const short8 a[2][4], const uint4* __restrict__ Xs4,
                                       int row, int g, f32x4 acc[2][4]) {
  #pragma unroll
  for (int kc = 0; kc < 4; ++kc) {
    #pragma unroll
    for (int nt = 0; nt < 4; ++nt) {
      int p = nt*16 + row;
      short8 bfr = *(const short8*)&Xs4[p*16 + ((kc*4 + g) ^ (p & 7))];
      acc[0][nt] = __builtin_amdgcn_mfma_f32_16x16x32_bf16(a[0][kc], bfr, acc[0][nt], 0, 0, 0);
      acc[1][nt] = __builtin_amdgcn_mfma_f32_16x16x32_bf16(a[1][kc], bfr, acc[1][nt], 0, 0, 0);
    }
  }
}

// ---------------- phi GEMM (MFMA): linxi[pt][c] = Wphi @ featB[pt] + bphi ----------------
__global__ __launch_bounds__(256) void phi_kernel(const u16* __restrict__ featB,
                                                  const u16* __restrict__ WphiB,
                                                  const float* __restrict__ bphi,
                                                  float* __restrict__ linxi)
{
  __shared__ uint4 Xs4[64*16];
  int tid = threadIdx.x, lane = tid & 63, wid = tid >> 6;
  int row = lane & 15, g = lane >> 4, m0 = wid * 32;
  size_t g0 = (size_t)blockIdx.x * 64;
  for (int u = tid; u < 1024; u += 256) {
    int p = u >> 4, seg = u & 15;
    Xs4[p*16 + (seg ^ (p & 7))] = *(const uint4*)&featB[(g0 + p)*128 + seg*8];
  }
  __syncthreads();
  short8 afr[2][4];
  load_af(WphiB, m0, row, g, afr);
  f32x4 acc[2][4];
  zero_acc(acc);
  gemm64(afr, Xs4, row, g, acc);
  #pragma unroll
  for (int mt = 0; mt < 2; ++mt) {
    int c = m0 + mt*16 + g*4;
    float4 bp = *(const float4*)&bphi[c];
    const float* bpp = (const float*)&bp;
    #pragma unroll
    for (int nt = 0; nt < 4; ++nt) {
      int p = nt*16 + row;
      float4 v = make_float4(acc[mt][nt][0]+bpp[0], acc[mt][nt][1]+bpp[1],
                             acc[mt][nt][2]+bpp[2], acc[mt][nt][3]+bpp[3]);
      *(float4*)&linxi[(g0 + p)*128 + c] = v;
    }
  }
}

// ---------------- pos second moments: per-block partials (deterministic) ----------------
__global__ __launch_bounds__(256) void pos_stats(const float* __restrict__ xyz,
                                                 const int* __restrict__ idx,
                                                 double* __restrict__ part)
{
  __shared__ double rd[256];
  int qg = blockIdx.x*256 + threadIdx.x;
  int b = qg >> 12, n = qg & 4095;
  const float* X = xyz + (size_t)b * 12288;
  float qx = X[n], qy = X[4096+n], qz = X[8192+n];
  double l[9] = {0,0,0,0,0,0,0,0,0};
  for (int kk = 0; kk < 16; ++kk) {
    int nb = idx[(size_t)qg*16 + kk];
    float px = qx - X[nb], py = qy - X[4096+nb], pz = qz - X[8192+nb];
    l[0] += px; l[1] += py; l[2] += pz;
    l[3] += (double)px*px; l[4] += (double)px*py; l[5] += (double)px*pz;
    l[6] += (double)py*py; l[7] += (double)py*pz; l[8] += (double)pz*pz;
  }
  for (int j = 0; j < 9; ++j) {
    __syncthreads();
    rd[threadIdx.x] = l[j];
    __syncthreads();
    for (int s = 128; s > 0; s >>= 1) {
      if (threadIdx.x < s) rd[threadIdx.x] += rd[threadIdx.x + s];
      __syncthreads();
    }
    if (threadIdx.x == 0) part[(size_t)blockIdx.x*9 + j] = rd[0];
  }
}

// ---------------- fold theta BN analytically ----------------
__global__ __launch_bounds__(128) void theta_fold(const double* __restrict__ part,
                                                  const float* __restrict__ Wc,
                                                  const float* __restrict__ bc,
                                                  const float* __restrict__ g,
                                                  const float* __restrict__ be,
                                                  float* __restrict__ WdT,
                                                  float* __restrict__ bd)
{
  int c = threadIdx.x;
  double st[9];
  for (int j = 0; j < 9; ++j) {
    double s = 0.0;
    for (int bk = 0; bk < 32; ++bk) s += part[(size_t)bk*9 + j];
    st[j] = s;
  }
  const double cnt = (double)NNPTS;
  double m0 = st[0]/cnt, m1 = st[1]/cnt, m2 = st[2]/cnt;
  double Pxx = st[3]/cnt, Pxy = st[4]/cnt, Pxz = st[5]/cnt;
  double Pyy = st[6]/cnt, Pyz = st[7]/cnt, Pzz = st[8]/cnt;
  double w0 = Wc[c*3], w1 = Wc[c*3+1], w2 = Wc[c*3+2], bb = bc[c];
  double wm = w0*m0 + w1*m1 + w2*m2;
  double mu = wm + bb;
  double quad = w0*(Pxx*w0 + Pxy*w1 + Pxz*w2)
              + w1*(Pxy*w0 + Pyy*w1 + Pyz*w2)
              + w2*(Pxz*w0 + Pyz*w1 + Pzz*w2);
  double Ex2 = quad + 2.0*bb*wm + bb*bb;
  double var = Ex2 - mu*mu;
  double s = (double)g[c] / sqrt(var + 1e-5);
  double t = (double)be[c] - s*mu;
  WdT[0*128+c] = (float)(s*w0);
  WdT[1*128+c] = (float)(s*w1);
  WdT[2*128+c] = (float)(s*w2);
  bd[c] = (float)(s*bb + t);
}

// ---------------- gamma BN stats reduce (double, deterministic) ----------------
__global__ __launch_bounds__(128) void gamma_reduce(const float* __restrict__ gs,
                                                    const float* __restrict__ gq,
                                                    const float* __restrict__ g,
                                                    const float* __restrict__ be,
                                                    float* __restrict__ s2,
                                                    float* __restrict__ t2v)
{
  int c = threadIdx.x;
  double S = 0.0, Q = 0.0;
  for (int bk = 0; bk < 2048; ++bk) {
    S += gs[(size_t)bk*128 + c];
    Q += gq[(size_t)bk*128 + c];
  }
  const double cnt = (double)NNPTS;
  double m = S/cnt, v = Q/cnt - m*m;
  double s = (double)g[c] / sqrt(v + 1e-5);
  s2[c]  = (float)s;
  t2v[c] = (float)((double)be[c] - s*m);
}

// ---------------- main MFMA pass: PASS=1 stats, PASS=2 final ----------------
template<int PASS>
__global__ __launch_bounds__(256) void pass_kernel(
    const u16* __restrict__ featB, const float* __restrict__ linxi,
    const int* __restrict__ idx, const float* __restrict__ xyz,
    const u16* __restrict__ WpsiB, const float* __restrict__ bpsi,
    const u16* __restrict__ WfusB, const float* __restrict__ c0,
    const float* __restrict__ WdT, const float* __restrict__ bd,
    const u16* __restrict__ WalphaB, const float* __restrict__ balpha,
    const float* __restrict__ s2, const float* __restrict__ t2,
    float* __restrict__ gs, float* __restrict__ gq,
    float* __restrict__ out)
{
  __shared__ uint4 Xs4[64*16];                 // gathered features, bf16 swizzled
  __shared__ u16   Rs[64*128];                 // rel0 bf16, same swizzle
  __shared__ float LxS[4][128];
  __shared__ float posS[3][64];
  __shared__ int   pidx[64];
  __shared__ float redS[128], redQ[128];

  int tid = threadIdx.x, lane = tid & 63, wid = tid >> 6;
  int row = lane & 15, g = lane >> 4;
  int m0 = wid * 32;
  int q0 = blockIdx.x * 4, b = q0 >> 12, n0 = q0 & 4095;
  const float* X = xyz + (size_t)b * 12288;

  if (tid < 64) {
    int q = tid >> 4;
    int nb = idx[(size_t)(q0 + q)*16 + (tid & 15)];
    pidx[tid] = nb;
    int nq = n0 + q;
    posS[0][tid] = X[nq]      - X[nb];
    posS[1][tid] = X[4096+nq] - X[4096+nb];
    posS[2][tid] = X[8192+nq] - X[8192+nb];
  }
  for (int u = tid; u < 512; u += 256)
    LxS[u >> 7][u & 127] = linxi[(size_t)q0*128 + u];
  __syncthreads();
  {
    const u16* fb = featB + ((size_t)b << 12) * 128;
    for (int u = tid; u < 1024; u += 256) {
      int p = u >> 4, seg = u & 15;
      Xs4[p*16 + (seg ^ (p & 7))] = *(const uint4*)&fb[(size_t)pidx[p]*128 + seg*8];
    }
  }

  // per-lane channel constants (channel base per mt)
  float4 bpsV[2], wd0V[2], wd1V[2], wd2V[2], bdV[2], c0V[2];
  #pragma unroll
  for (int mt = 0; mt < 2; ++mt) {
    int c = m0 + mt*16 + g*4;
    bpsV[mt] = *(const float4*)&bpsi[c];
    wd0V[mt] = *(const float4*)&WdT[c];
    wd1V[mt] = *(const float4*)&WdT[128 + c];
    wd2V[mt] = *(const float4*)&WdT[256 + c];
    bdV[mt]  = *(const float4*)&bd[c];
    c0V[mt]  = *(const float4*)&c0[c];
  }
  __syncthreads();

  short8 afr[2][4];
  f32x4 accA[2][4];

  // ---- psi GEMM ----
  load_af(WpsiB, m0, row, g, afr);
  zero_acc(accA);
  gemm64(afr, Xs4, row, g, accA);

  // ---- rel0 = lin_xi - (psi+b) + delta  -> Rs (bf16, swizzled) ----
  #pragma unroll
  for (int mt = 0; mt < 2; ++mt) {
    int c = m0 + mt*16 + g*4;
    const float* bps = (const float*)&bpsV[mt];
    const float* w0p = (const float*)&wd0V[mt];
    const float* w1p = (const float*)&wd1V[mt];
    const float* w2p = (const float*)&wd2V[mt];
    const float* bdp = (const float*)&bdV[mt];
    #pragma unroll
    for (int nt = 0; nt < 4; ++nt) {
      int p = nt*16 + row;
      float p0 = posS[0][p], p1 = posS[1][p], p2 = posS[2][p];
      const float* lx = &LxS[nt][c];
      ushort4 wvv;
      u16* wvp = (u16*)&wvv;
      #pragma unroll
      for (int r = 0; r < 4; ++r) {
        float d = fmaf(w2p[r], p2, fmaf(w1p[r], p1, fmaf(w0p[r], p0, bdp[r])));
        d = fmaxf(d, 0.f);
        wvp[r] = f2bf(lx[r] - (accA[mt][nt][r] + bps[r]) + d);
      }
      *(ushort4*)&Rs[p*128 + (c ^ ((p & 7) << 3))] = wvv;
    }
  }
  __syncthreads();

  // ---- fused gamma GEMM on rel0 ----
  load_af(WfusB, m0, row, g, afr);
  zero_acc(accA);
  gemm64(afr, (const uint4*)Rs, row, g, accA);

  if (PASS == 1) {
    #pragma unroll
    for (int mt = 0; mt < 2; ++mt) {
      int c = m0 + mt*16 + g*4;
      const float* c0p = (const float*)&c0V[mt];
      float sv[4], qv[4];
      #pragma unroll
      for (int r = 0; r < 4; ++r) {
        float s = 0.f, qq = 0.f;
        #pragma unroll
        for (int nt = 0; nt < 4; ++nt) {
          float gg = accA[mt][nt][r] + c0p[r];
          s += gg; qq = fmaf(gg, gg, qq);
        }
        #pragma unroll
        for (int d = 1; d < 16; d <<= 1) { s += __shfl_xor(s, d); qq += __shfl_xor(qq, d); }
        sv[r] = s; qv[r] = qq;
      }
      if (row == 0) {
        *(float4*)&redS[c] = make_float4(sv[0], sv[1], sv[2], sv[3]);
        *(float4*)&redQ[c] = make_float4(qv[0], qv[1], qv[2], qv[3]);
      }
    }
    __syncthreads();
    if (tid < 128) {
      gs[(size_t)blockIdx.x*128 + tid] = redS[tid];
      gq[(size_t)blockIdx.x*128 + tid] = redQ[tid];
    }
    return;
  }

  // ---- PASS 2: alpha GEMM (Xs4 still intact) ----
  f32x4 accB[2][4];
  load_af(WalphaB, m0, row, g, afr);
  zero_acc(accB);
  gemm64(afr, Xs4, row, g, accB);

  #pragma unroll
  for (int mt = 0; mt < 2; ++mt) {
    int c = m0 + mt*16 + g*4;
    float4 s2V = *(const float4*)&s2[c];
    float4 t2V = *(const float4*)&t2[c];
    float4 baV = *(const float4*)&balpha[c];
    const float* s2p = (const float*)&s2V;
    const float* t2p = (const float*)&t2V;
    const float* bap = (const float*)&baV;
    const float* c0p = (const float*)&c0V[mt];
    const float* w0p = (const float*)&wd0V[mt];
    const float* w1p = (const float*)&wd1V[mt];
    const float* w2p = (const float*)&wd2V[mt];
    const float* bdp = (const float*)&bdV[mt];
    #pragma unroll
    for (int nt = 0; nt < 4; ++nt) {
      int p = nt*16 + row;
      float p0 = posS[0][p], p1 = posS[1][p], p2 = posS[2][p];
      float ov[4];
      #pragma unroll
      for (int r = 0; r < 4; ++r) {
        float gg = accA[mt][nt][r] + c0p[r];
        float rel = fmaxf(fmaf(s2p[r], gg, t2p[r]), 0.f);
        float d = fmaf(w2p[r], p2, fmaf(w1p[r], p1, fmaf(w0p[r], p0, bdp[r])));
        d = fmaxf(d, 0.f);
        float F = accB[mt][nt][r] + bap[r] + d;
        float mx = rel;
        #pragma unroll
        for (int dd = 1; dd < 16; dd <<= 1) mx = fmaxf(mx, __shfl_xor(mx, dd));
        float e = expf(rel - mx);
        float se = e, so = e * F;
        #pragma unroll
        for (int dd = 1; dd < 16; dd <<= 1) { se += __shfl_xor(se, dd); so += __shfl_xor(so, dd); }
        ov[r] = so / se;
      }
      if (row == 0) {
        #pragma unroll
        for (int r = 0; r < 4; ++r)
          out[(((size_t)b*128 + c + r) << 12) + (n0 + nt)] = ov[r];
      }
    }
  }
}

extern "C" void kernel_launch(void* const* d_in, const int* in_sizes, int n_in,
                              void* d_out, int out_size, void* d_ws, size_t ws_size,
                              hipStream_t stream)
{
  const float* xyz      = (const float*)d_in[0];
  const float* features = (const float*)d_in[1];
  const float* wt1      = (const float*)d_in[2];
  const float* bt1      = (const float*)d_in[3];
  const float* wt2      = (const float*)d_in[4];
  const float* bt2      = (const float*)d_in[5];
  const float* gth      = (const float*)d_in[6];
  const float* bth      = (const float*)d_in[7];
  const float* wphi     = (const float*)d_in[8];
  const float* bphi     = (const float*)d_in[9];
  const float* wpsi     = (const float*)d_in[10];
  const float* bpsi     = (const float*)d_in[11];
  const float* walpha   = (const float*)d_in[12];
  const float* balpha   = (const float*)d_in[13];
  const float* wg1      = (const float*)d_in[14];
  const float* bg1      = (const float*)d_in[15];
  const float* wg2      = (const float*)d_in[16];
  const float* bg2      = (const float*)d_in[17];
  const float* gga      = (const float*)d_in[18];
  const float* bga      = (const float*)d_in[19];

  char* w = (char*)d_ws;
  size_t off = 0;
  auto take = [&](size_t bytes) -> void* {
    void* p = w + off;
    off = (off + bytes + 255) & ~(size_t)255;
    return p;
  };
  int*    idxW    = (int*)   take((size_t)NQ*16*4);
  u16*    featB   = (u16*)   take((size_t)NQ*128*2);
  float*  linxi   = (float*) take((size_t)NQ*128*4);
  u16*    WphiB   = (u16*)   take(32768);
  u16*    WpsiB   = (u16*)   take(32768);
  u16*    WalphaB = (u16*)   take(32768);
  u16*    WfusB   = (u16*)   take(32768);
  float*  c0      = (float*) take(512);
  float*  Wc      = (float*) take(1536);
  float*  bc      = (float*) take(512);
  float*  WdT     = (float*) take(1536);
  float*  bd      = (float*) take(512);
  double* part    = (double*)take(32*9*8);
  float*  gs      = (float*) take((size_t)2048*128*4);
  float*  gq      = (float*) take((size_t)2048*128*4);
  float*  s2      = (float*) take(512);
  float*  t2v     = (float*) take(512);
  float*  out     = (float*)d_out;

  transpose_feat<<<dim3(64, 2, 2), 256, 0, stream>>>(features, featB);
  prep_weights<<<128, 128, 0, stream>>>(wphi, wpsi, walpha, wg1, wg2, bg1, bg2,
                                        wt1, bt1, wt2, bt2,
                                        WphiB, WpsiB, WalphaB, WfusB, c0, Wc, bc);
  knn_kernel<<<8192, 256, 0, stream>>>(xyz, idxW);
  phi_kernel<<<128, 256, 0, stream>>>(featB, WphiB, bphi, linxi);
  pos_stats<<<32, 256, 0, stream>>>(xyz, idxW, part);
  theta_fold<<<1, 128, 0, stream>>>(part, Wc, bc, gth, bth, WdT, bd);
  pass_kernel<1><<<2048, 256, 0, stream>>>(featB, linxi, idxW, xyz,
      WpsiB, bpsi, WfusB, c0, WdT, bd, WalphaB, balpha, s2, t2v, gs, gq, out);
  gamma_reduce<<<1, 128, 0, stream>>>(gs, gq, gga, bga, s2, t2v);
  pass_kernel<2><<<2048, 256, 0, stream>>>(featB, linxi, idxW, xyz,
      WpsiB, bpsi, WfusB, c0, WdT, bd, WalphaB, balpha, s2, t2v, gs, gq, out);
}

// Round 3
// 298.423 us; speedup vs baseline: 2.8591x; 1.5180x over previous
//
#include <hip/hip_runtime.h>
#include <math.h>

typedef __attribute__((ext_vector_type(8))) short short8;
typedef __attribute__((ext_vector_type(4))) float f32x4;
typedef unsigned short u16;

#define NNPTS 131072          // B*N*K
#define NQ    8192            // B*N

__device__ __forceinline__ u16 f2bf(float f) {
  unsigned u = __float_as_uint(f);
  u = u + 0x7fffu + ((u >> 16) & 1u);
  return (u16)(u >> 16);
}

// ---------------- transpose features [B][C][N] -> featB bf16 [B][N][C] ----------------
__global__ __launch_bounds__(256) void transpose_feat(const float* __restrict__ f,
                                                      u16* __restrict__ featB)
{
  __shared__ float T[64][65];
  int tx = threadIdx.x & 63, tg = threadIdx.x >> 6;
  int n0 = blockIdx.x * 64, c0 = blockIdx.y * 64, b = blockIdx.z;
  const float* src = f + ((size_t)b * 128 + c0) * 4096 + n0;
  #pragma unroll
  for (int it = 0; it < 16; ++it) {
    int cl = tg + it * 4;
    T[cl][tx] = src[(size_t)cl * 4096 + tx];
  }
  __syncthreads();
  u16* dst = featB + ((size_t)b * 4096 + n0) * 128 + c0;
  #pragma unroll
  for (int it = 0; it < 16; ++it) {
    int nl = tg + it * 4;
    dst[(size_t)nl * 128 + tx] = f2bf(T[tx][nl]);
  }
}

// ---------------- weight prep: bf16 casts + fused products ----------------
__global__ __launch_bounds__(128) void prep_weights(
    const float* __restrict__ wphi, const float* __restrict__ wpsi,
    const float* __restrict__ walpha,
    const float* __restrict__ wg1, const float* __restrict__ wg2,
    const float* __restrict__ bg1, const float* __restrict__ bg2,
    const float* __restrict__ wt1, const float* __restrict__ bt1,
    const float* __restrict__ wt2, const float* __restrict__ bt2,
    u16* __restrict__ WphiB, u16* __restrict__ WpsiB, u16* __restrict__ WalphaB,
    u16* __restrict__ WfusB, float* __restrict__ c0,
    float* __restrict__ Wc, float* __restrict__ bc)
{
  int cc = blockIdx.x, i = threadIdx.x;
  WphiB[cc*128+i]   = f2bf(wphi[cc*128+i]);
  WpsiB[cc*128+i]   = f2bf(wpsi[cc*128+i]);
  WalphaB[cc*128+i] = f2bf(walpha[cc*128+i]);
  float s = 0.f;
  for (int t = 0; t < 128; ++t) s = fmaf(wg2[cc*128+t], wg1[t*128+i], s);
  WfusB[cc*128+i] = f2bf(s);
  if (i == 0) {
    float s0 = bg2[cc];
    for (int t = 0; t < 128; ++t) s0 = fmaf(wg2[cc*128+t], bg1[t], s0);
    c0[cc] = s0;
    for (int j = 0; j < 3; ++j) {
      float a = 0.f;
      for (int t = 0; t < 128; ++t) a = fmaf(wt2[cc*128+t], wt1[t*3+j], a);
      Wc[cc*3+j] = a;
    }
    float bb = bt2[cc];
    for (int t = 0; t < 128; ++t) bb = fmaf(wt2[cc*128+t], bt1[t], bb);
    bc[cc] = bb;
  }
}

// ---------------- KNN: wave per query, register top-4 lists, no barriers ----------------
__global__ __launch_bounds__(256) void knn_kernel(const float* __restrict__ xyz,
                                                  int* __restrict__ idxOut)
{
  int tid = threadIdx.x, lane = tid & 63, wid = tid >> 6;
  int q = blockIdx.x * 4 + wid;
  int b = q >> 12, n = q & 4095;
  const float* X = xyz + (size_t)b * 12288;
  float qx = X[n], qy = X[4096+n], qz = X[8192+n];
  float xxq = __fadd_rn(__fadd_rn(__fmul_rn(qx,qx), __fmul_rn(qy,qy)), __fmul_rn(qz,qz));

  float v0=-INFINITY, v1=-INFINITY, v2=-INFINITY, v3=-INFINITY;
  int   i0=0x7fffffff, i1=0x7fffffff, i2=0x7fffffff, i3=0x7fffffff;
  unsigned long long alive = ~0ull;

  #pragma unroll 4
  for (int j = 0; j < 64; ++j) {
    int m = j*64 + lane;
    float mx = X[m], my = X[4096+m], mz = X[8192+m];
    float xxm = __fadd_rn(__fadd_rn(__fmul_rn(mx,mx), __fmul_rn(my,my)), __fmul_rn(mz,mz));
    float dot = __fadd_rn(__fadd_rn(__fmul_rn(qx,mx), __fmul_rn(qy,my)), __fmul_rn(qz,mz));
    float inner = __fmul_rn(-2.0f, dot);
    float dv = __fsub_rn(__fsub_rn(-xxm, inner), xxq);   // exact ref order
    bool c0_ = dv > v0, c1_ = dv > v1, c2_ = dv > v2, c3_ = dv > v3;
    float nv1 = c0_ ? v0 : (c1_ ? dv : v1); int ni1 = c0_ ? i0 : (c1_ ? m : i1);
    float nv2 = c1_ ? v1 : (c2_ ? dv : v2); int ni2 = c1_ ? i1 : (c2_ ? m : i2);
    float nv3 = c2_ ? v2 : (c3_ ? dv : v3); int ni3 = c2_ ? i2 : (c3_ ? m : i3);
    v0 = c0_ ? dv : v0; i0 = c0_ ? m : i0;
    v1 = nv1; i1 = ni1; v2 = nv2; i2 = ni2; v3 = nv3; i3 = ni3;
  }

  int cnt = 4;
  for (int r = 0; r < 16; ++r) {
    float gv = v0; int gi = i0;
    #pragma unroll
    for (int d = 1; d < 64; d <<= 1) {
      float ov = __shfl_xor(gv, d); int oi = __shfl_xor(gi, d);
      if (ov > gv || (ov == gv && oi < gi)) { gv = ov; gi = oi; }
    }
    if (lane == 0) idxOut[(size_t)q*16 + r] = gi;
    if (lane == (gi & 63)) {
      alive &= ~(1ull << (gi >> 6));
      v0=v1; i0=i1; v1=v2; i1=i2; v2=v3; i2=i3; v3=-INFINITY; i3=0x7fffffff;
      if (--cnt == 0 && r < 15) {
        // rare: this lane supplied 4 of the top so far -> rebuild from alive set
        v0=v1=v2=v3=-INFINITY; i0=i1=i2=i3=0x7fffffff;
        for (int j = 0; j < 64; ++j) {
          if (!((alive >> j) & 1ull)) continue;
          int m = j*64 + lane;
          float mx = X[m], my = X[4096+m], mz = X[8192+m];
          float xxm = __fadd_rn(__fadd_rn(__fmul_rn(mx,mx), __fmul_rn(my,my)), __fmul_rn(mz,mz));
          float dot = __fadd_rn(__fadd_rn(__fmul_rn(qx,mx), __fmul_rn(qy,my)), __fmul_rn(qz,mz));
          float inner = __fmul_rn(-2.0f, dot);
          float dv = __fsub_rn(__fsub_rn(-xxm, inner), xxq);
          bool c0_ = dv > v0, c1_ = dv > v1, c2_ = dv > v2, c3_ = dv > v3;
          float nv1 = c0_ ? v0 : (c1_ ? dv : v1); int ni1 = c0_ ? i0 : (c1_ ? m : i1);
          float nv2 = c1_ ? v1 : (c2_ ? dv : v2); int ni2 = c1_ ? i1 : (c2_ ? m : i2);
          float nv3 = c2_ ? v2 : (c3_ ? dv : v3); int ni3 = c2_ ? i2 : (c3_ ? m : i3);
          v0 = c0_ ? dv : v0; i0 = c0_ ? m : i0;
          v1 = nv1; i1 = ni1; v2 = nv2; i2 = ni2; v3 = nv3; i3 = ni3;
        }
        cnt = 4;
      }
    }
  }
}

// ---------------- MFMA helpers ----------------
__device__ __forceinline__ void zero_acc(f32x4 a[2][4]) {
  #pragma unroll
  for (int mt = 0; mt < 2; ++mt)
    #pragma unroll
    for (int nt = 0; nt < 4; ++nt)
      a[mt][nt] = (f32x4){0.f, 0.f, 0.f, 0.f};
}

__device__ __forceinline__ void load_af(const u16* __restrict__ WB, int m0, int row, int g,
                                        short8 a[2][4]) {
  #pragma unroll
  for (int mt = 0; mt < 2; ++mt)
    #pragma unroll
    for (int kc = 0; kc < 4; ++kc)
      a[mt][kc] = *(const short8*)&WB[(size_t)(m0 + mt*16 + row)*128 + kc*32 + g*8];
}

__device__ __forceinline__ void gemm64(const short8 a[2][4], const uint4* __restrict__ Xs4,
                                       int row, int g, f32x4 acc[2][4]) {
  #pragma unroll
  for (int kc = 0; kc < 4; ++kc) {
    #pragma unroll
    for (int nt = 0; nt < 4; ++nt) {
      int p = nt*16 + row;
      short8 bfr = *(const short8*)&Xs4[p*16 + ((kc*4 + g) ^ (p & 7))];
      acc[0][nt] = __builtin_amdgcn_mfma_f32_16x16x32_bf16(a[0][kc], bfr, acc[0][nt], 0, 0, 0);
      acc[1][nt] = __builtin_amdgcn_mfma_f32_16x16x32_bf16(a[1][kc], bfr, acc[1][nt], 0, 0, 0);
    }
  }
}

// ---------------- phi GEMM (MFMA): linxi[pt][c] = Wphi @ featB[pt] + bphi ----------------
__global__ __launch_bounds__(256) void phi_kernel(const u16* __restrict__ featB,
                                                  const u16* __restrict__ WphiB,
                                                  const float* __restrict__ bphi,
                                                  float* __restrict__ linxi)
{
  __shared__ uint4 Xs4[64*16];
  int tid = threadIdx.x, lane = tid & 63, wid = tid >> 6;
  int row = lane & 15, g = lane >> 4, m0 = wid * 32;
  size_t g0 = (size_t)blockIdx.x * 64;
  for (int u = tid; u < 1024; u += 256) {
    int p = u >> 4, seg = u & 15;
    Xs4[p*16 + (seg ^ (p & 7))] = *(const uint4*)&featB[(g0 + p)*128 + seg*8];
  }
  __syncthreads();
  short8 afr[2][4];
  load_af(WphiB, m0, row, g, afr);
  f32x4 acc[2][4];
  zero_acc(acc);
  gemm64(afr, Xs4, row, g, acc);
  #pragma unroll
  for (int mt = 0; mt < 2; ++mt) {
    int c = m0 + mt*16 + g*4;
    float4 bp = *(const float4*)&bphi[c];
    const float* bpp = (const float*)&bp;
    #pragma unroll
    for (int nt = 0; nt < 4; ++nt) {
      int p = nt*16 + row;
      float4 v = make_float4(acc[mt][nt][0]+bpp[0], acc[mt][nt][1]+bpp[1],
                             acc[mt][nt][2]+bpp[2], acc[mt][nt][3]+bpp[3]);
      *(float4*)&linxi[(g0 + p)*128 + c] = v;
    }
  }
}

// ---------------- pos second moments: per-block partials (deterministic) ----------------
__global__ __launch_bounds__(256) void pos_stats(const float* __restrict__ xyz,
                                                 const int* __restrict__ idx,
                                                 double* __restrict__ part)
{
  __shared__ double rd[256];
  int qg = blockIdx.x*256 + threadIdx.x;
  int b = qg >> 12, n = qg & 4095;
  const float* X = xyz + (size_t)b * 12288;
  float qx = X[n], qy = X[4096+n], qz = X[8192+n];
  double l[9] = {0,0,0,0,0,0,0,0,0};
  for (int kk = 0; kk < 16; ++kk) {
    int nb = idx[(size_t)qg*16 + kk];
    float px = qx - X[nb], py = qy - X[4096+nb], pz = qz - X[8192+nb];
    l[0] += px; l[1] += py; l[2] += pz;
    l[3] += (double)px*px; l[4] += (double)px*py; l[5] += (double)px*pz;
    l[6] += (double)py*py; l[7] += (double)py*pz; l[8] += (double)pz*pz;
  }
  for (int j = 0; j < 9; ++j) {
    __syncthreads();
    rd[threadIdx.x] = l[j];
    __syncthreads();
    for (int s = 128; s > 0; s >>= 1) {
      if (threadIdx.x < s) rd[threadIdx.x] += rd[threadIdx.x + s];
      __syncthreads();
    }
    if (threadIdx.x == 0) part[(size_t)blockIdx.x*9 + j] = rd[0];
  }
}

// ---------------- fold theta BN analytically ----------------
__global__ __launch_bounds__(128) void theta_fold(const double* __restrict__ part,
                                                  const float* __restrict__ Wc,
                                                  const float* __restrict__ bc,
                                                  const float* __restrict__ g,
                                                  const float* __restrict__ be,
                                                  float* __restrict__ WdT,
                                                  float* __restrict__ bd)
{
  int c = threadIdx.x;
  double st[9];
  for (int j = 0; j < 9; ++j) {
    double s = 0.0;
    for (int bk = 0; bk < 32; ++bk) s += part[(size_t)bk*9 + j];
    st[j] = s;
  }
  const double cnt = (double)NNPTS;
  double m0 = st[0]/cnt, m1 = st[1]/cnt, m2 = st[2]/cnt;
  double Pxx = st[3]/cnt, Pxy = st[4]/cnt, Pxz = st[5]/cnt;
  double Pyy = st[6]/cnt, Pyz = st[7]/cnt, Pzz = st[8]/cnt;
  double w0 = Wc[c*3], w1 = Wc[c*3+1], w2 = Wc[c*3+2], bb = bc[c];
  double wm = w0*m0 + w1*m1 + w2*m2;
  double mu = wm + bb;
  double quad = w0*(Pxx*w0 + Pxy*w1 + Pxz*w2)
              + w1*(Pxy*w0 + Pyy*w1 + Pyz*w2)
              + w2*(Pxz*w0 + Pyz*w1 + Pzz*w2);
  double Ex2 = quad + 2.0*bb*wm + bb*bb;
  double var = Ex2 - mu*mu;
  double s = (double)g[c] / sqrt(var + 1e-5);
  double t = (double)be[c] - s*mu;
  WdT[0*128+c] = (float)(s*w0);
  WdT[1*128+c] = (float)(s*w1);
  WdT[2*128+c] = (float)(s*w2);
  bd[c] = (float)(s*bb + t);
}

// ---------------- gamma BN stats reduce (double, deterministic) ----------------
__global__ __launch_bounds__(128) void gamma_reduce(const float* __restrict__ gs,
                                                    const float* __restrict__ gq,
                                                    const float* __restrict__ g,
                                                    const float* __restrict__ be,
                                                    float* __restrict__ s2,
                                                    float* __restrict__ t2v)
{
  int c = threadIdx.x;
  double S = 0.0, Q = 0.0;
  for (int bk = 0; bk < 2048; ++bk) {
    S += gs[(size_t)bk*128 + c];
    Q += gq[(size_t)bk*128 + c];
  }
  const double cnt = (double)NNPTS;
  double m = S/cnt, v = Q/cnt - m*m;
  double s = (double)g[c] / sqrt(v + 1e-5);
  s2[c]  = (float)s;
  t2v[c] = (float)((double)be[c] - s*m);
}

// ---------------- main MFMA pass: PASS=1 stats, PASS=2 final ----------------
template<int PASS>
__global__ __launch_bounds__(256) void pass_kernel(
    const u16* __restrict__ featB, const float* __restrict__ linxi,
    const int* __restrict__ idx, const float* __restrict__ xyz,
    const u16* __restrict__ WpsiB, const float* __restrict__ bpsi,
    const u16* __restrict__ WfusB, const float* __restrict__ c0,
    const float* __restrict__ WdT, const float* __restrict__ bd,
    const u16* __restrict__ WalphaB, const float* __restrict__ balpha,
    const float* __restrict__ s2, const float* __restrict__ t2,
    float* __restrict__ gs, float* __restrict__ gq,
    float* __restrict__ out)
{
  __shared__ uint4 Xs4[64*16];                 // gathered features, bf16 swizzled
  __shared__ u16   Rs[64*128];                 // rel0 bf16, same swizzle
  __shared__ float LxS[4][128];
  __shared__ float posS[3][64];
  __shared__ int   pidx[64];
  __shared__ float redS[128], redQ[128];

  int tid = threadIdx.x, lane = tid & 63, wid = tid >> 6;
  int row = lane & 15, g = lane >> 4;
  int m0 = wid * 32;
  int q0 = blockIdx.x * 4, b = q0 >> 12, n0 = q0 & 4095;
  const float* X = xyz + (size_t)b * 12288;

  if (tid < 64) {
    int q = tid >> 4;
    int nb = idx[(size_t)(q0 + q)*16 + (tid & 15)];
    pidx[tid] = nb;
    int nq = n0 + q;
    posS[0][tid] = X[nq]      - X[nb];
    posS[1][tid] = X[4096+nq] - X[4096+nb];
    posS[2][tid] = X[8192+nq] - X[8192+nb];
  }
  for (int u = tid; u < 512; u += 256)
    LxS[u >> 7][u & 127] = linxi[(size_t)q0*128 + u];
  __syncthreads();
  {
    const u16* fb = featB + ((size_t)b << 12) * 128;
    for (int u = tid; u < 1024; u += 256) {
      int p = u >> 4, seg = u & 15;
      Xs4[p*16 + (seg ^ (p & 7))] = *(const uint4*)&fb[(size_t)pidx[p]*128 + seg*8];
    }
  }

  // per-lane channel constants (channel base per mt)
  float4 bpsV[2], wd0V[2], wd1V[2], wd2V[2], bdV[2], c0V[2];
  #pragma unroll
  for (int mt = 0; mt < 2; ++mt) {
    int c = m0 + mt*16 + g*4;
    bpsV[mt] = *(const float4*)&bpsi[c];
    wd0V[mt] = *(const float4*)&WdT[c];
    wd1V[mt] = *(const float4*)&WdT[128 + c];
    wd2V[mt] = *(const float4*)&WdT[256 + c];
    bdV[mt]  = *(const float4*)&bd[c];
    c0V[mt]  = *(const float4*)&c0[c];
  }
  __syncthreads();

  short8 afr[2][4];
  f32x4 accA[2][4];

  // ---- psi GEMM ----
  load_af(WpsiB, m0, row, g, afr);
  zero_acc(accA);
  gemm64(afr, Xs4, row, g, accA);

  // ---- rel0 = lin_xi - (psi+b) + delta  -> Rs (bf16, swizzled) ----
  #pragma unroll
  for (int mt = 0; mt < 2; ++mt) {
    int c = m0 + mt*16 + g*4;
    const float* bps = (const float*)&bpsV[mt];
    const float* w0p = (const float*)&wd0V[mt];
    const float* w1p = (const float*)&wd1V[mt];
    const float* w2p = (const float*)&wd2V[mt];
    const float* bdp = (const float*)&bdV[mt];
    #pragma unroll
    for (int nt = 0; nt < 4; ++nt) {
      int p = nt*16 + row;
      float p0 = posS[0][p], p1 = posS[1][p], p2 = posS[2][p];
      const float* lx = &LxS[nt][c];
      ushort4 wvv;
      u16* wvp = (u16*)&wvv;
      #pragma unroll
      for (int r = 0; r < 4; ++r) {
        float d = fmaf(w2p[r], p2, fmaf(w1p[r], p1, fmaf(w0p[r], p0, bdp[r])));
        d = fmaxf(d, 0.f);
        wvp[r] = f2bf(lx[r] - (accA[mt][nt][r] + bps[r]) + d);
      }
      *(ushort4*)&Rs[p*128 + (c ^ ((p & 7) << 3))] = wvv;
    }
  }
  __syncthreads();

  // ---- fused gamma GEMM on rel0 ----
  load_af(WfusB, m0, row, g, afr);
  zero_acc(accA);
  gemm64(afr, (const uint4*)Rs, row, g, accA);

  if (PASS == 1) {
    #pragma unroll
    for (int mt = 0; mt < 2; ++mt) {
      int c = m0 + mt*16 + g*4;
      const float* c0p = (const float*)&c0V[mt];
      float sv[4], qv[4];
      #pragma unroll
      for (int r = 0; r < 4; ++r) {
        float s = 0.f, qq = 0.f;
        #pragma unroll
        for (int nt = 0; nt < 4; ++nt) {
          float gg = accA[mt][nt][r] + c0p[r];
          s += gg; qq = fmaf(gg, gg, qq);
        }
        #pragma unroll
        for (int d = 1; d < 16; d <<= 1) { s += __shfl_xor(s, d); qq += __shfl_xor(qq, d); }
        sv[r] = s; qv[r] = qq;
      }
      if (row == 0) {
        *(float4*)&redS[c] = make_float4(sv[0], sv[1], sv[2], sv[3]);
        *(float4*)&redQ[c] = make_float4(qv[0], qv[1], qv[2], qv[3]);
      }
    }
    __syncthreads();
    if (tid < 128) {
      gs[(size_t)blockIdx.x*128 + tid] = redS[tid];
      gq[(size_t)blockIdx.x*128 + tid] = redQ[tid];
    }
    return;
  }

  // ---- PASS 2: alpha GEMM (Xs4 still intact) ----
  f32x4 accB[2][4];
  load_af(WalphaB, m0, row, g, afr);
  zero_acc(accB);
  gemm64(afr, Xs4, row, g, accB);

  #pragma unroll
  for (int mt = 0; mt < 2; ++mt) {
    int c = m0 + mt*16 + g*4;
    float4 s2V = *(const float4*)&s2[c];
    float4 t2V = *(const float4*)&t2[c];
    float4 baV = *(const float4*)&balpha[c];
    const float* s2p = (const float*)&s2V;
    const float* t2p = (const float*)&t2V;
    const float* bap = (const float*)&baV;
    const float* c0p = (const float*)&c0V[mt];
    const float* w0p = (const float*)&wd0V[mt];
    const float* w1p = (const float*)&wd1V[mt];
    const float* w2p = (const float*)&wd2V[mt];
    const float* bdp = (const float*)&bdV[mt];
    #pragma unroll
    for (int nt = 0; nt < 4; ++nt) {
      int p = nt*16 + row;
      float p0 = posS[0][p], p1 = posS[1][p], p2 = posS[2][p];
      float ov[4];
      #pragma unroll
      for (int r = 0; r < 4; ++r) {
        float gg = accA[mt][nt][r] + c0p[r];
        float rel = fmaxf(fmaf(s2p[r], gg, t2p[r]), 0.f);
        float d = fmaf(w2p[r], p2, fmaf(w1p[r], p1, fmaf(w0p[r], p0, bdp[r])));
        d = fmaxf(d, 0.f);
        float F = accB[mt][nt][r] + bap[r] + d;
        float mx = rel;
        #pragma unroll
        for (int dd = 1; dd < 16; dd <<= 1) mx = fmaxf(mx, __shfl_xor(mx, dd));
        float e = expf(rel - mx);
        float se = e, so = e * F;
        #pragma unroll
        for (int dd = 1; dd < 16; dd <<= 1) { se += __shfl_xor(se, dd); so += __shfl_xor(so, dd); }
        ov[r] = so / se;
      }
      if (row == 0) {
        #pragma unroll
        for (int r = 0; r < 4; ++r)
          out[(((size_t)b*128 + c + r) << 12) + (n0 + nt)] = ov[r];
      }
    }
  }
}

extern "C" void kernel_launch(void* const* d_in, const int* in_sizes, int n_in,
                              void* d_out, int out_size, void* d_ws, size_t ws_size,
                              hipStream_t stream)
{
  const float* xyz      = (const float*)d_in[0];
  const float* features = (const float*)d_in[1];
  const float* wt1      = (const float*)d_in[2];
  const float* bt1      = (const float*)d_in[3];
  const float* wt2      = (const float*)d_in[4];
  const float* bt2      = (const float*)d_in[5];
  const float* gth      = (const float*)d_in[6];
  const float* bth      = (const float*)d_in[7];
  const float* wphi     = (const float*)d_in[8];
  const float* bphi     = (const float*)d_in[9];
  const float* wpsi     = (const float*)d_in[10];
  const float* bpsi     = (const float*)d_in[11];
  const float* walpha   = (const float*)d_in[12];
  const float* balpha   = (const float*)d_in[13];
  const float* wg1      = (const float*)d_in[14];
  const float* bg1      = (const float*)d_in[15];
  const float* wg2      = (const float*)d_in[16];
  const float* bg2      = (const float*)d_in[17];
  const float* gga      = (const float*)d_in[18];
  const float* bga      = (const float*)d_in[19];

  char* w = (char*)d_ws;
  size_t off = 0;
  auto take = [&](size_t bytes) -> void* {
    void* p = w + off;
    off = (off + bytes + 255) & ~(size_t)255;
    return p;
  };
  int*    idxW    = (int*)   take((size_t)NQ*16*4);
  u16*    featB   = (u16*)   take((size_t)NQ*128*2);
  float*  linxi   = (float*) take((size_t)NQ*128*4);
  u16*    WphiB   = (u16*)   take(32768);
  u16*    WpsiB   = (u16*)   take(32768);
  u16*    WalphaB = (u16*)   take(32768);
  u16*    WfusB   = (u16*)   take(32768);
  float*  c0      = (float*) take(512);
  float*  Wc      = (float*) take(1536);
  float*  bc      = (float*) take(512);
  float*  WdT     = (float*) take(1536);
  float*  bd      = (float*) take(512);
  double* part    = (double*)take(32*9*8);
  float*  gs      = (float*) take((size_t)2048*128*4);
  float*  gq      = (float*) take((size_t)2048*128*4);
  float*  s2      = (float*) take(512);
  float*  t2v     = (float*) take(512);
  float*  out     = (float*)d_out;

  transpose_feat<<<dim3(64, 2, 2), 256, 0, stream>>>(features, featB);
  prep_weights<<<128, 128, 0, stream>>>(wphi, wpsi, walpha, wg1, wg2, bg1, bg2,
                                        wt1, bt1, wt2, bt2,
                                        WphiB, WpsiB, WalphaB, WfusB, c0, Wc, bc);
  knn_kernel<<<2048, 256, 0, stream>>>(xyz, idxW);
  phi_kernel<<<128, 256, 0, stream>>>(featB, WphiB, bphi, linxi);
  pos_stats<<<32, 256, 0, stream>>>(xyz, idxW, part);
  theta_fold<<<1, 128, 0, stream>>>(part, Wc, bc, gth, bth, WdT, bd);
  pass_kernel<1><<<2048, 256, 0, stream>>>(featB, linxi, idxW, xyz,
      WpsiB, bpsi, WfusB, c0, WdT, bd, WalphaB, balpha, s2, t2v, gs, gq, out);
  gamma_reduce<<<1, 128, 0, stream>>>(gs, gq, gga, bga, s2, t2v);
  pass_kernel<2><<<2048, 256, 0, stream>>>(featB, linxi, idxW, xyz,
      WpsiB, bpsi, WfusB, c0, WdT, bd, WalphaB, balpha, s2, t2v, gs, gq, out);
}

// Round 4
// 212.580 us; speedup vs baseline: 4.0136x; 1.4038x over previous
//
#include <hip/hip_runtime.h>
#include <math.h>

typedef __attribute__((ext_vector_type(8))) short short8;
typedef __attribute__((ext_vector_type(4))) float f32x4;
typedef unsigned short u16;

#define NNPTS 131072          // B*N*K
#define NQ    8192            // B*N

__device__ __forceinline__ u16 f2bf(float f) {
  unsigned u = __float_as_uint(f);
  u = u + 0x7fffu + ((u >> 16) & 1u);
  return (u16)(u >> 16);
}

// ---------------- transpose features [B][C][N] -> featB bf16 [B][N][C] ----------------
__global__ __launch_bounds__(256) void transpose_feat(const float* __restrict__ f,
                                                      u16* __restrict__ featB)
{
  __shared__ float T[64][65];
  int tx = threadIdx.x & 63, tg = threadIdx.x >> 6;
  int n0 = blockIdx.x * 64, c0 = blockIdx.y * 64, b = blockIdx.z;
  const float* src = f + ((size_t)b * 128 + c0) * 4096 + n0;
  #pragma unroll
  for (int it = 0; it < 16; ++it) {
    int cl = tg + it * 4;
    T[cl][tx] = src[(size_t)cl * 4096 + tx];
  }
  __syncthreads();
  u16* dst = featB + ((size_t)b * 4096 + n0) * 128 + c0;
  #pragma unroll
  for (int it = 0; it < 16; ++it) {
    int nl = tg + it * 4;
    dst[(size_t)nl * 128 + tx] = f2bf(T[tx][nl]);
  }
}

// ---------------- weight prep: bf16 casts + fused products ----------------
__global__ __launch_bounds__(128) void prep_weights(
    const float* __restrict__ wphi, const float* __restrict__ wpsi,
    const float* __restrict__ walpha,
    const float* __restrict__ wg1, const float* __restrict__ wg2,
    const float* __restrict__ bg1, const float* __restrict__ bg2,
    const float* __restrict__ wt1, const float* __restrict__ bt1,
    const float* __restrict__ wt2, const float* __restrict__ bt2,
    u16* __restrict__ WphiB, u16* __restrict__ WpsiB, u16* __restrict__ WalphaB,
    u16* __restrict__ WfusB, float* __restrict__ c0,
    float* __restrict__ Wc, float* __restrict__ bc)
{
  int cc = blockIdx.x, i = threadIdx.x;
  WphiB[cc*128+i]   = f2bf(wphi[cc*128+i]);
  WpsiB[cc*128+i]   = f2bf(wpsi[cc*128+i]);
  WalphaB[cc*128+i] = f2bf(walpha[cc*128+i]);
  float s = 0.f;
  for (int t = 0; t < 128; ++t) s = fmaf(wg2[cc*128+t], wg1[t*128+i], s);
  WfusB[cc*128+i] = f2bf(s);
  if (i == 0) {
    float s0 = bg2[cc];
    for (int t = 0; t < 128; ++t) s0 = fmaf(wg2[cc*128+t], bg1[t], s0);
    c0[cc] = s0;
    for (int j = 0; j < 3; ++j) {
      float a = 0.f;
      for (int t = 0; t < 128; ++t) a = fmaf(wt2[cc*128+t], wt1[t*3+j], a);
      Wc[cc*3+j] = a;
    }
    float bb = bt2[cc];
    for (int t = 0; t < 128; ++t) bb = fmaf(wt2[cc*128+t], bt1[t], bb);
    bc[cc] = bb;
  }
}

// ---------------- KNN: wave per query, register top-4 lists, no barriers ----------------
__global__ __launch_bounds__(256) void knn_kernel(const float* __restrict__ xyz,
                                                  int* __restrict__ idxOut)
{
  int tid = threadIdx.x, lane = tid & 63, wid = tid >> 6;
  int q = blockIdx.x * 4 + wid;
  int b = q >> 12, n = q & 4095;
  const float* X = xyz + (size_t)b * 12288;
  float qx = X[n], qy = X[4096+n], qz = X[8192+n];
  float xxq = __fadd_rn(__fadd_rn(__fmul_rn(qx,qx), __fmul_rn(qy,qy)), __fmul_rn(qz,qz));

  float v0=-INFINITY, v1=-INFINITY, v2=-INFINITY, v3=-INFINITY;
  int   i0=0x7fffffff, i1=0x7fffffff, i2=0x7fffffff, i3=0x7fffffff;
  unsigned long long alive = ~0ull;

  #pragma unroll 4
  for (int j = 0; j < 64; ++j) {
    int m = j*64 + lane;
    float mx = X[m], my = X[4096+m], mz = X[8192+m];
    float xxm = __fadd_rn(__fadd_rn(__fmul_rn(mx,mx), __fmul_rn(my,my)), __fmul_rn(mz,mz));
    float dot = __fadd_rn(__fadd_rn(__fmul_rn(qx,mx), __fmul_rn(qy,my)), __fmul_rn(qz,mz));
    float inner = __fmul_rn(-2.0f, dot);
    float dv = __fsub_rn(__fsub_rn(-xxm, inner), xxq);   // exact ref order
    bool c0_ = dv > v0, c1_ = dv > v1, c2_ = dv > v2, c3_ = dv > v3;
    float nv1 = c0_ ? v0 : (c1_ ? dv : v1); int ni1 = c0_ ? i0 : (c1_ ? m : i1);
    float nv2 = c1_ ? v1 : (c2_ ? dv : v2); int ni2 = c1_ ? i1 : (c2_ ? m : i2);
    float nv3 = c2_ ? v2 : (c3_ ? dv : v3); int ni3 = c2_ ? i2 : (c3_ ? m : i3);
    v0 = c0_ ? dv : v0; i0 = c0_ ? m : i0;
    v1 = nv1; i1 = ni1; v2 = nv2; i2 = ni2; v3 = nv3; i3 = ni3;
  }

  int cnt = 4;
  for (int r = 0; r < 16; ++r) {
    float gv = v0; int gi = i0;
    #pragma unroll
    for (int d = 1; d < 64; d <<= 1) {
      float ov = __shfl_xor(gv, d); int oi = __shfl_xor(gi, d);
      if (ov > gv || (ov == gv && oi < gi)) { gv = ov; gi = oi; }
    }
    if (lane == 0) idxOut[(size_t)q*16 + r] = gi;
    if (lane == (gi & 63)) {
      alive &= ~(1ull << (gi >> 6));
      v0=v1; i0=i1; v1=v2; i1=i2; v2=v3; i2=i3; v3=-INFINITY; i3=0x7fffffff;
      if (--cnt == 0 && r < 15) {
        // rare: this lane supplied 4 of the top so far -> rebuild from alive set
        v0=v1=v2=v3=-INFINITY; i0=i1=i2=i3=0x7fffffff;
        for (int j = 0; j < 64; ++j) {
          if (!((alive >> j) & 1ull)) continue;
          int m = j*64 + lane;
          float mx = X[m], my = X[4096+m], mz = X[8192+m];
          float xxm = __fadd_rn(__fadd_rn(__fmul_rn(mx,mx), __fmul_rn(my,my)), __fmul_rn(mz,mz));
          float dot = __fadd_rn(__fadd_rn(__fmul_rn(qx,mx), __fmul_rn(qy,my)), __fmul_rn(qz,mz));
          float inner = __fmul_rn(-2.0f, dot);
          float dv = __fsub_rn(__fsub_rn(-xxm, inner), xxq);
          bool c0_ = dv > v0, c1_ = dv > v1, c2_ = dv > v2, c3_ = dv > v3;
          float nv1 = c0_ ? v0 : (c1_ ? dv : v1); int ni1 = c0_ ? i0 : (c1_ ? m : i1);
          float nv2 = c1_ ? v1 : (c2_ ? dv : v2); int ni2 = c1_ ? i1 : (c2_ ? m : i2);
          float nv3 = c2_ ? v2 : (c3_ ? dv : v3); int ni3 = c2_ ? i2 : (c3_ ? m : i3);
          v0 = c0_ ? dv : v0; i0 = c0_ ? m : i0;
          v1 = nv1; i1 = ni1; v2 = nv2; i2 = ni2; v3 = nv3; i3 = ni3;
        }
        cnt = 4;
      }
    }
  }
}

// ---------------- MFMA helpers ----------------
__device__ __forceinline__ void zero_acc(f32x4 a[2][4]) {
  #pragma unroll
  for (int mt = 0; mt < 2; ++mt)
    #pragma unroll
    for (int nt = 0; nt < 4; ++nt)
      a[mt][nt] = (f32x4){0.f, 0.f, 0.f, 0.f};
}

__device__ __forceinline__ void load_af(const u16* __restrict__ WB, int m0, int row, int g,
                                        short8 a[2][4]) {
  #pragma unroll
  for (int mt = 0; mt < 2; ++mt)
    #pragma unroll
    for (int kc = 0; kc < 4; ++kc)
      a[mt][kc] = *(const short8*)&WB[(size_t)(m0 + mt*16 + row)*128 + kc*32 + g*8];
}

__device__ __forceinline__ void gemm64(const short8 a[2][4], const uint4* __restrict__ Xs4,
                                       int row, int g, f32x4 acc[2][4]) {
  #pragma unroll
  for (int kc = 0; kc < 4; ++kc) {
    #pragma unroll
    for (int nt = 0; nt < 4; ++nt) {
      int p = nt*16 + row;
      short8 bfr = *(const short8*)&Xs4[p*16 + ((kc*4 + g) ^ (p & 7))];
      acc[0][nt] = __builtin_amdgcn_mfma_f32_16x16x32_bf16(a[0][kc], bfr, acc[0][nt], 0, 0, 0);
      acc[1][nt] = __builtin_amdgcn_mfma_f32_16x16x32_bf16(a[1][kc], bfr, acc[1][nt], 0, 0, 0);
    }
  }
}

// ---------------- phi GEMM (MFMA): linxi[pt][c] = Wphi @ featB[pt] + bphi ----------------
__global__ __launch_bounds__(256) void phi_kernel(const u16* __restrict__ featB,
                                                  const u16* __restrict__ WphiB,
                                                  const float* __restrict__ bphi,
                                                  float* __restrict__ linxi)
{
  __shared__ uint4 Xs4[64*16];
  int tid = threadIdx.x, lane = tid & 63, wid = tid >> 6;
  int row = lane & 15, g = lane >> 4, m0 = wid * 32;
  size_t g0 = (size_t)blockIdx.x * 64;
  for (int u = tid; u < 1024; u += 256) {
    int p = u >> 4, seg = u & 15;
    Xs4[p*16 + (seg ^ (p & 7))] = *(const uint4*)&featB[(g0 + p)*128 + seg*8];
  }
  __syncthreads();
  short8 afr[2][4];
  load_af(WphiB, m0, row, g, afr);
  f32x4 acc[2][4];
  zero_acc(acc);
  gemm64(afr, Xs4, row, g, acc);
  #pragma unroll
  for (int mt = 0; mt < 2; ++mt) {
    int c = m0 + mt*16 + g*4;
    float4 bp = *(const float4*)&bphi[c];
    const float* bpp = (const float*)&bp;
    #pragma unroll
    for (int nt = 0; nt < 4; ++nt) {
      int p = nt*16 + row;
      float4 v = make_float4(acc[mt][nt][0]+bpp[0], acc[mt][nt][1]+bpp[1],
                             acc[mt][nt][2]+bpp[2], acc[mt][nt][3]+bpp[3]);
      *(float4*)&linxi[(g0 + p)*128 + c] = v;
    }
  }
}

// ---------------- pos second moments: per-block partials (deterministic) ----------------
__global__ __launch_bounds__(256) void pos_stats(const float* __restrict__ xyz,
                                                 const int* __restrict__ idx,
                                                 double* __restrict__ part)
{
  __shared__ double rd[256];
  int qg = blockIdx.x*256 + threadIdx.x;
  int b = qg >> 12, n = qg & 4095;
  const float* X = xyz + (size_t)b * 12288;
  float qx = X[n], qy = X[4096+n], qz = X[8192+n];
  double l[9] = {0,0,0,0,0,0,0,0,0};
  for (int kk = 0; kk < 16; ++kk) {
    int nb = idx[(size_t)qg*16 + kk];
    float px = qx - X[nb], py = qy - X[4096+nb], pz = qz - X[8192+nb];
    l[0] += px; l[1] += py; l[2] += pz;
    l[3] += (double)px*px; l[4] += (double)px*py; l[5] += (double)px*pz;
    l[6] += (double)py*py; l[7] += (double)py*pz; l[8] += (double)pz*pz;
  }
  for (int j = 0; j < 9; ++j) {
    __syncthreads();
    rd[threadIdx.x] = l[j];
    __syncthreads();
    for (int s = 128; s > 0; s >>= 1) {
      if (threadIdx.x < s) rd[threadIdx.x] += rd[threadIdx.x + s];
      __syncthreads();
    }
    if (threadIdx.x == 0) part[(size_t)blockIdx.x*9 + j] = rd[0];
  }
}

// ---------------- fold theta BN analytically ----------------
__global__ __launch_bounds__(128) void theta_fold(const double* __restrict__ part,
                                                  const float* __restrict__ Wc,
                                                  const float* __restrict__ bc,
                                                  const float* __restrict__ g,
                                                  const float* __restrict__ be,
                                                  float* __restrict__ WdT,
                                                  float* __restrict__ bd)
{
  int c = threadIdx.x;
  double st[9];
  for (int j = 0; j < 9; ++j) {
    double s = 0.0;
    for (int bk = 0; bk < 32; ++bk) s += part[(size_t)bk*9 + j];
    st[j] = s;
  }
  const double cnt = (double)NNPTS;
  double m0 = st[0]/cnt, m1 = st[1]/cnt, m2 = st[2]/cnt;
  double Pxx = st[3]/cnt, Pxy = st[4]/cnt, Pxz = st[5]/cnt;
  double Pyy = st[6]/cnt, Pyz = st[7]/cnt, Pzz = st[8]/cnt;
  double w0 = Wc[c*3], w1 = Wc[c*3+1], w2 = Wc[c*3+2], bb = bc[c];
  double wm = w0*m0 + w1*m1 + w2*m2;
  double mu = wm + bb;
  double quad = w0*(Pxx*w0 + Pxy*w1 + Pxz*w2)
              + w1*(Pxy*w0 + Pyy*w1 + Pyz*w2)
              + w2*(Pxz*w0 + Pyz*w1 + Pzz*w2);
  double Ex2 = quad + 2.0*bb*wm + bb*bb;
  double var = Ex2 - mu*mu;
  double s = (double)g[c] / sqrt(var + 1e-5);
  double t = (double)be[c] - s*mu;
  WdT[0*128+c] = (float)(s*w0);
  WdT[1*128+c] = (float)(s*w1);
  WdT[2*128+c] = (float)(s*w2);
  bd[c] = (float)(s*bb + t);
}

// ---------------- gamma BN stats: stage 1 (64 blocks x 32 rows, double) ----------------
__global__ __launch_bounds__(256) void gamma_part(const float* __restrict__ gs,
                                                  const float* __restrict__ gq,
                                                  double* __restrict__ partS,
                                                  double* __restrict__ partQ)
{
  int c = threadIdx.x & 127;
  int arr = threadIdx.x >> 7;
  int j = blockIdx.x;
  const float* src = arr ? gq : gs;
  double s = 0.0;
  #pragma unroll 8
  for (int bk = j*32; bk < j*32 + 32; ++bk)
    s += src[(size_t)bk*128 + c];
  (arr ? partQ : partS)[(size_t)j*128 + c] = s;
}

// ---------------- gamma BN stats: stage 2 (final fold) ----------------
__global__ __launch_bounds__(128) void gamma_final(const double* __restrict__ partS,
                                                   const double* __restrict__ partQ,
                                                   const float* __restrict__ g,
                                                   const float* __restrict__ be,
                                                   float* __restrict__ s2,
                                                   float* __restrict__ t2v)
{
  int c = threadIdx.x;
  double S = 0.0, Q = 0.0;
  #pragma unroll 8
  for (int j = 0; j < 64; ++j) {
    S += partS[(size_t)j*128 + c];
    Q += partQ[(size_t)j*128 + c];
  }
  const double cnt = (double)NNPTS;
  double m = S/cnt, v = Q/cnt - m*m;
  double s = (double)g[c] / sqrt(v + 1e-5);
  s2[c]  = (float)s;
  t2v[c] = (float)((double)be[c] - s*m);
}

// ---------------- main MFMA pass: PASS=1 stats, PASS=2 final ----------------
template<int PASS>
__global__ __launch_bounds__(256) void pass_kernel(
    const u16* __restrict__ featB, const float* __restrict__ linxi,
    const int* __restrict__ idx, const float* __restrict__ xyz,
    const u16* __restrict__ WpsiB, const float* __restrict__ bpsi,
    const u16* __restrict__ WfusB, const float* __restrict__ c0,
    const float* __restrict__ WdT, const float* __restrict__ bd,
    const u16* __restrict__ WalphaB, const float* __restrict__ balpha,
    const float* __restrict__ s2, const float* __restrict__ t2,
    float* __restrict__ gs, float* __restrict__ gq,
    float* __restrict__ out)
{
  __shared__ uint4 Xs4[64*16];                 // gathered features, bf16 swizzled
  __shared__ u16   Rs[64*128];                 // rel0 bf16, same swizzle
  __shared__ float LxS[4][128];
  __shared__ float posS[3][64];
  __shared__ int   pidx[64];
  __shared__ float redS[128], redQ[128];

  int tid = threadIdx.x, lane = tid & 63, wid = tid >> 6;
  int row = lane & 15, g = lane >> 4;
  int m0 = wid * 32;
  int q0 = blockIdx.x * 4, b = q0 >> 12, n0 = q0 & 4095;
  const float* X = xyz + (size_t)b * 12288;

  if (tid < 64) {
    int q = tid >> 4;
    int nb = idx[(size_t)(q0 + q)*16 + (tid & 15)];
    pidx[tid] = nb;
    int nq = n0 + q;
    posS[0][tid] = X[nq]      - X[nb];
    posS[1][tid] = X[4096+nq] - X[4096+nb];
    posS[2][tid] = X[8192+nq] - X[8192+nb];
  }
  for (int u = tid; u < 512; u += 256)
    LxS[u >> 7][u & 127] = linxi[(size_t)q0*128 + u];
  __syncthreads();
  {
    const u16* fb = featB + ((size_t)b << 12) * 128;
    for (int u = tid; u < 1024; u += 256) {
      int p = u >> 4, seg = u & 15;
      Xs4[p*16 + (seg ^ (p & 7))] = *(const uint4*)&fb[(size_t)pidx[p]*128 + seg*8];
    }
  }

  // per-lane channel constants (channel base per mt)
  float4 bpsV[2], wd0V[2], wd1V[2], wd2V[2], bdV[2], c0V[2];
  #pragma unroll
  for (int mt = 0; mt < 2; ++mt) {
    int c = m0 + mt*16 + g*4;
    bpsV[mt] = *(const float4*)&bpsi[c];
    wd0V[mt] = *(const float4*)&WdT[c];
    wd1V[mt] = *(const float4*)&WdT[128 + c];
    wd2V[mt] = *(const float4*)&WdT[256 + c];
    bdV[mt]  = *(const float4*)&bd[c];
    c0V[mt]  = *(const float4*)&c0[c];
  }
  __syncthreads();

  short8 afr[2][4];
  f32x4 accA[2][4];

  // ---- psi GEMM ----
  load_af(WpsiB, m0, row, g, afr);
  zero_acc(accA);
  gemm64(afr, Xs4, row, g, accA);

  // ---- rel0 = lin_xi - (psi+b) + delta  -> Rs (bf16, swizzled) ----
  #pragma unroll
  for (int mt = 0; mt < 2; ++mt) {
    int c = m0 + mt*16 + g*4;
    const float* bps = (const float*)&bpsV[mt];
    const float* w0p = (const float*)&wd0V[mt];
    const float* w1p = (const float*)&wd1V[mt];
    const float* w2p = (const float*)&wd2V[mt];
    const float* bdp = (const float*)&bdV[mt];
    #pragma unroll
    for (int nt = 0; nt < 4; ++nt) {
      int p = nt*16 + row;
      float p0 = posS[0][p], p1 = posS[1][p], p2 = posS[2][p];
      const float* lx = &LxS[nt][c];
      ushort4 wvv;
      u16* wvp = (u16*)&wvv;
      #pragma unroll
      for (int r = 0; r < 4; ++r) {
        float d = fmaf(w2p[r], p2, fmaf(w1p[r], p1, fmaf(w0p[r], p0, bdp[r])));
        d = fmaxf(d, 0.f);
        wvp[r] = f2bf(lx[r] - (accA[mt][nt][r] + bps[r]) + d);
      }
      *(ushort4*)&Rs[p*128 + (c ^ ((p & 7) << 3))] = wvv;
    }
  }
  __syncthreads();

  // ---- fused gamma GEMM on rel0 ----
  load_af(WfusB, m0, row, g, afr);
  zero_acc(accA);
  gemm64(afr, (const uint4*)Rs, row, g, accA);

  if (PASS == 1) {
    #pragma unroll
    for (int mt = 0; mt < 2; ++mt) {
      int c = m0 + mt*16 + g*4;
      const float* c0p = (const float*)&c0V[mt];
      float sv[4], qv[4];
      #pragma unroll
      for (int r = 0; r < 4; ++r) {
        float s = 0.f, qq = 0.f;
        #pragma unroll
        for (int nt = 0; nt < 4; ++nt) {
          float gg = accA[mt][nt][r] + c0p[r];
          s += gg; qq = fmaf(gg, gg, qq);
        }
        #pragma unroll
        for (int d = 1; d < 16; d <<= 1) { s += __shfl_xor(s, d); qq += __shfl_xor(qq, d); }
        sv[r] = s; qv[r] = qq;
      }
      if (row == 0) {
        *(float4*)&redS[c] = make_float4(sv[0], sv[1], sv[2], sv[3]);
        *(float4*)&redQ[c] = make_float4(qv[0], qv[1], qv[2], qv[3]);
      }
    }
    __syncthreads();
    if (tid < 128) {
      gs[(size_t)blockIdx.x*128 + tid] = redS[tid];
      gq[(size_t)blockIdx.x*128 + tid] = redQ[tid];
    }
    return;
  }

  // ---- PASS 2: alpha GEMM (Xs4 still intact) ----
  f32x4 accB[2][4];
  load_af(WalphaB, m0, row, g, afr);
  zero_acc(accB);
  gemm64(afr, Xs4, row, g, accB);

  #pragma unroll
  for (int mt = 0; mt < 2; ++mt) {
    int c = m0 + mt*16 + g*4;
    float4 s2V = *(const float4*)&s2[c];
    float4 t2V = *(const float4*)&t2[c];
    float4 baV = *(const float4*)&balpha[c];
    const float* s2p = (const float*)&s2V;
    const float* t2p = (const float*)&t2V;
    const float* bap = (const float*)&baV;
    const float* c0p = (const float*)&c0V[mt];
    const float* w0p = (const float*)&wd0V[mt];
    const float* w1p = (const float*)&wd1V[mt];
    const float* w2p = (const float*)&wd2V[mt];
    const float* bdp = (const float*)&bdV[mt];
    #pragma unroll
    for (int nt = 0; nt < 4; ++nt) {
      int p = nt*16 + row;
      float p0 = posS[0][p], p1 = posS[1][p], p2 = posS[2][p];
      float ov[4];
      #pragma unroll
      for (int r = 0; r < 4; ++r) {
        float gg = accA[mt][nt][r] + c0p[r];
        float rel = fmaxf(fmaf(s2p[r], gg, t2p[r]), 0.f);
        float d = fmaf(w2p[r], p2, fmaf(w1p[r], p1, fmaf(w0p[r], p0, bdp[r])));
        d = fmaxf(d, 0.f);
        float F = accB[mt][nt][r] + bap[r] + d;
        float mx = rel;
        #pragma unroll
        for (int dd = 1; dd < 16; dd <<= 1) mx = fmaxf(mx, __shfl_xor(mx, dd));
        float e = expf(rel - mx);
        float se = e, so = e * F;
        #pragma unroll
        for (int dd = 1; dd < 16; dd <<= 1) { se += __shfl_xor(se, dd); so += __shfl_xor(so, dd); }
        ov[r] = so / se;
      }
      if (row == 0) {
        #pragma unroll
        for (int r = 0; r < 4; ++r)
          out[(((size_t)b*128 + c + r) << 12) + (n0 + nt)] = ov[r];
      }
    }
  }
}

extern "C" void kernel_launch(void* const* d_in, const int* in_sizes, int n_in,
                              void* d_out, int out_size, void* d_ws, size_t ws_size,
                              hipStream_t stream)
{
  const float* xyz      = (const float*)d_in[0];
  const float* features = (const float*)d_in[1];
  const float* wt1      = (const float*)d_in[2];
  const float* bt1      = (const float*)d_in[3];
  const float* wt2      = (const float*)d_in[4];
  const float* bt2      = (const float*)d_in[5];
  const float* gth      = (const float*)d_in[6];
  const float* bth      = (const float*)d_in[7];
  const float* wphi     = (const float*)d_in[8];
  const float* bphi     = (const float*)d_in[9];
  const float* wpsi     = (const float*)d_in[10];
  const float* bpsi     = (const float*)d_in[11];
  const float* walpha   = (const float*)d_in[12];
  const float* balpha   = (const float*)d_in[13];
  const float* wg1      = (const float*)d_in[14];
  const float* bg1      = (const float*)d_in[15];
  const float* wg2      = (const float*)d_in[16];
  const float* bg2      = (const float*)d_in[17];
  const float* gga      = (const float*)d_in[18];
  const float* bga      = (const float*)d_in[19];

  char* w = (char*)d_ws;
  size_t off = 0;
  auto take = [&](size_t bytes) -> void* {
    void* p = w + off;
    off = (off + bytes + 255) & ~(size_t)255;
    return p;
  };
  int*    idxW    = (int*)   take((size_t)NQ*16*4);
  u16*    featB   = (u16*)   take((size_t)NQ*128*2);
  float*  linxi   = (float*) take((size_t)NQ*128*4);
  u16*    WphiB   = (u16*)   take(32768);
  u16*    WpsiB   = (u16*)   take(32768);
  u16*    WalphaB = (u16*)   take(32768);
  u16*    WfusB   = (u16*)   take(32768);
  float*  c0      = (float*) take(512);
  float*  Wc      = (float*) take(1536);
  float*  bc      = (float*) take(512);
  float*  WdT     = (float*) take(1536);
  float*  bd      = (float*) take(512);
  double* part    = (double*)take(32*9*8);
  float*  gs      = (float*) take((size_t)2048*128*4);
  float*  gq      = (float*) take((size_t)2048*128*4);
  double* partS   = (double*)take((size_t)64*128*8);
  double* partQ   = (double*)take((size_t)64*128*8);
  float*  s2      = (float*) take(512);
  float*  t2v     = (float*) take(512);
  float*  out     = (float*)d_out;

  transpose_feat<<<dim3(64, 2, 2), 256, 0, stream>>>(features, featB);
  prep_weights<<<128, 128, 0, stream>>>(wphi, wpsi, walpha, wg1, wg2, bg1, bg2,
                                        wt1, bt1, wt2, bt2,
                                        WphiB, WpsiB, WalphaB, WfusB, c0, Wc, bc);
  knn_kernel<<<2048, 256, 0, stream>>>(xyz, idxW);
  phi_kernel<<<128, 256, 0, stream>>>(featB, WphiB, bphi, linxi);
  pos_stats<<<32, 256, 0, stream>>>(xyz, idxW, part);
  theta_fold<<<1, 128, 0, stream>>>(part, Wc, bc, gth, bth, WdT, bd);
  pass_kernel<1><<<2048, 256, 0, stream>>>(featB, linxi, idxW, xyz,
      WpsiB, bpsi, WfusB, c0, WdT, bd, WalphaB, balpha, s2, t2v, gs, gq, out);
  gamma_part<<<64, 256, 0, stream>>>(gs, gq, partS, partQ);
  gamma_final<<<1, 128, 0, stream>>>(partS, partQ, gga, bga, s2, t2v);
  pass_kernel<2><<<2048, 256, 0, stream>>>(featB, linxi, idxW, xyz,
      WpsiB, bpsi, WfusB, c0, WdT, bd, WalphaB, balpha, s2, t2v, gs, gq, out);
}

// Round 5
// 194.810 us; speedup vs baseline: 4.3797x; 1.0912x over previous
//
#include <hip/hip_runtime.h>
#include <math.h>

typedef __attribute__((ext_vector_type(8))) short short8;
typedef __attribute__((ext_vector_type(4))) float f32x4;
typedef unsigned short u16;

#define NNPTS 131072          // B*N*K
#define NQ    8192            // B*N

__device__ __forceinline__ u16 f2bf(float f) {
  unsigned u = __float_as_uint(f);
  u = u + 0x7fffu + ((u >> 16) & 1u);
  return (u16)(u >> 16);
}

// ---------------- transpose features [B][C][N] -> featB bf16 [B][N][C] ----------------
__global__ __launch_bounds__(256) void transpose_feat(const float* __restrict__ f,
                                                      u16* __restrict__ featB)
{
  __shared__ float T[64][65];
  int tx = threadIdx.x & 63, tg = threadIdx.x >> 6;
  int n0 = blockIdx.x * 64, c0 = blockIdx.y * 64, b = blockIdx.z;
  const float* src = f + ((size_t)b * 128 + c0) * 4096 + n0;
  #pragma unroll
  for (int it = 0; it < 16; ++it) {
    int cl = tg + it * 4;
    T[cl][tx] = src[(size_t)cl * 4096 + tx];
  }
  __syncthreads();
  u16* dst = featB + ((size_t)b * 4096 + n0) * 128 + c0;
  #pragma unroll
  for (int it = 0; it < 16; ++it) {
    int nl = tg + it * 4;
    dst[(size_t)nl * 128 + tx] = f2bf(T[tx][nl]);
  }
}

// ---------------- weight prep: bf16 casts + fused products ----------------
__global__ __launch_bounds__(128) void prep_weights(
    const float* __restrict__ wphi, const float* __restrict__ wpsi,
    const float* __restrict__ walpha,
    const float* __restrict__ wg1, const float* __restrict__ wg2,
    const float* __restrict__ bg1, const float* __restrict__ bg2,
    const float* __restrict__ wt1, const float* __restrict__ bt1,
    const float* __restrict__ wt2, const float* __restrict__ bt2,
    u16* __restrict__ WphiB, u16* __restrict__ WpsiB, u16* __restrict__ WalphaB,
    u16* __restrict__ WfusB, float* __restrict__ c0,
    float* __restrict__ Wc, float* __restrict__ bc)
{
  int cc = blockIdx.x, i = threadIdx.x;
  WphiB[cc*128+i]   = f2bf(wphi[cc*128+i]);
  WpsiB[cc*128+i]   = f2bf(wpsi[cc*128+i]);
  WalphaB[cc*128+i] = f2bf(walpha[cc*128+i]);
  float s = 0.f;
  for (int t = 0; t < 128; ++t) s = fmaf(wg2[cc*128+t], wg1[t*128+i], s);
  WfusB[cc*128+i] = f2bf(s);
  if (i == 0) {
    float s0 = bg2[cc];
    for (int t = 0; t < 128; ++t) s0 = fmaf(wg2[cc*128+t], bg1[t], s0);
    c0[cc] = s0;
    for (int j = 0; j < 3; ++j) {
      float a = 0.f;
      for (int t = 0; t < 128; ++t) a = fmaf(wt2[cc*128+t], wt1[t*3+j], a);
      Wc[cc*3+j] = a;
    }
    float bb = bt2[cc];
    for (int t = 0; t < 128; ++t) bb = fmaf(wt2[cc*128+t], bt1[t], bb);
    bc[cc] = bb;
  }
}

// ---------------- KNN: wave per query, register top-4 lists, no barriers ----------------
__global__ __launch_bounds__(256) void knn_kernel(const float* __restrict__ xyz,
                                                  int* __restrict__ idxOut)
{
  int tid = threadIdx.x, lane = tid & 63, wid = tid >> 6;
  int q = blockIdx.x * 4 + wid;
  int b = q >> 12, n = q & 4095;
  const float* X = xyz + (size_t)b * 12288;
  float qx = X[n], qy = X[4096+n], qz = X[8192+n];
  float xxq = __fadd_rn(__fadd_rn(__fmul_rn(qx,qx), __fmul_rn(qy,qy)), __fmul_rn(qz,qz));

  float v0=-INFINITY, v1=-INFINITY, v2=-INFINITY, v3=-INFINITY;
  int   i0=0x7fffffff, i1=0x7fffffff, i2=0x7fffffff, i3=0x7fffffff;
  unsigned long long alive = ~0ull;

  #pragma unroll 4
  for (int j = 0; j < 64; ++j) {
    int m = j*64 + lane;
    float mx = X[m], my = X[4096+m], mz = X[8192+m];
    float xxm = __fadd_rn(__fadd_rn(__fmul_rn(mx,mx), __fmul_rn(my,my)), __fmul_rn(mz,mz));
    float dot = __fadd_rn(__fadd_rn(__fmul_rn(qx,mx), __fmul_rn(qy,my)), __fmul_rn(qz,mz));
    float inner = __fmul_rn(-2.0f, dot);
    float dv = __fsub_rn(__fsub_rn(-xxm, inner), xxq);   // exact ref order
    bool c0_ = dv > v0, c1_ = dv > v1, c2_ = dv > v2, c3_ = dv > v3;
    float nv1 = c0_ ? v0 : (c1_ ? dv : v1); int ni1 = c0_ ? i0 : (c1_ ? m : i1);
    float nv2 = c1_ ? v1 : (c2_ ? dv : v2); int ni2 = c1_ ? i1 : (c2_ ? m : i2);
    float nv3 = c2_ ? v2 : (c3_ ? dv : v3); int ni3 = c2_ ? i2 : (c3_ ? m : i3);
    v0 = c0_ ? dv : v0; i0 = c0_ ? m : i0;
    v1 = nv1; i1 = ni1; v2 = nv2; i2 = ni2; v3 = nv3; i3 = ni3;
  }

  int cnt = 4;
  for (int r = 0; r < 16; ++r) {
    float gv = v0; int gi = i0;
    #pragma unroll
    for (int d = 1; d < 64; d <<= 1) {
      float ov = __shfl_xor(gv, d); int oi = __shfl_xor(gi, d);
      if (ov > gv || (ov == gv && oi < gi)) { gv = ov; gi = oi; }
    }
    if (lane == 0) idxOut[(size_t)q*16 + r] = gi;
    if (lane == (gi & 63)) {
      alive &= ~(1ull << (gi >> 6));
      v0=v1; i0=i1; v1=v2; i1=i2; v2=v3; i2=i3; v3=-INFINITY; i3=0x7fffffff;
      if (--cnt == 0 && r < 15) {
        v0=v1=v2=v3=-INFINITY; i0=i1=i2=i3=0x7fffffff;
        for (int j = 0; j < 64; ++j) {
          if (!((alive >> j) & 1ull)) continue;
          int m = j*64 + lane;
          float mx = X[m], my = X[4096+m], mz = X[8192+m];
          float xxm = __fadd_rn(__fadd_rn(__fmul_rn(mx,mx), __fmul_rn(my,my)), __fmul_rn(mz,mz));
          float dot = __fadd_rn(__fadd_rn(__fmul_rn(qx,mx), __fmul_rn(qy,my)), __fmul_rn(qz,mz));
          float inner = __fmul_rn(-2.0f, dot);
          float dv = __fsub_rn(__fsub_rn(-xxm, inner), xxq);
          bool c0_ = dv > v0, c1_ = dv > v1, c2_ = dv > v2, c3_ = dv > v3;
          float nv1 = c0_ ? v0 : (c1_ ? dv : v1); int ni1 = c0_ ? i0 : (c1_ ? m : i1);
          float nv2 = c1_ ? v1 : (c2_ ? dv : v2); int ni2 = c1_ ? i1 : (c2_ ? m : i2);
          float nv3 = c2_ ? v2 : (c3_ ? dv : v3); int ni3 = c2_ ? i2 : (c3_ ? m : i3);
          v0 = c0_ ? dv : v0; i0 = c0_ ? m : i0;
          v1 = nv1; i1 = ni1; v2 = nv2; i2 = ni2; v3 = nv3; i3 = ni3;
        }
        cnt = 4;
      }
    }
  }
}

// ---------------- MFMA helpers ----------------
__device__ __forceinline__ void zero_acc(f32x4 a[2][4]) {
  #pragma unroll
  for (int mt = 0; mt < 2; ++mt)
    #pragma unroll
    for (int nt = 0; nt < 4; ++nt)
      a[mt][nt] = (f32x4){0.f, 0.f, 0.f, 0.f};
}

__device__ __forceinline__ void load_af(const u16* __restrict__ WB, int m0, int row, int g,
                                        short8 a[2][4]) {
  #pragma unroll
  for (int mt = 0; mt < 2; ++mt)
    #pragma unroll
    for (int kc = 0; kc < 4; ++kc)
      a[mt][kc] = *(const short8*)&WB[(size_t)(m0 + mt*16 + row)*128 + kc*32 + g*8];
}

__device__ __forceinline__ void gemm64(const short8 a[2][4], const uint4* __restrict__ Xs4,
                                       int row, int g, f32x4 acc[2][4]) {
  #pragma unroll
  for (int kc = 0; kc < 4; ++kc) {
    #pragma unroll
    for (int nt = 0; nt < 4; ++nt) {
      int p = nt*16 + row;
      short8 bfr = *(const short8*)&Xs4[p*16 + ((kc*4 + g) ^ (p & 7))];
      acc[0][nt] = __builtin_amdgcn_mfma_f32_16x16x32_bf16(a[0][kc], bfr, acc[0][nt], 0, 0, 0);
      acc[1][nt] = __builtin_amdgcn_mfma_f32_16x16x32_bf16(a[1][kc], bfr, acc[1][nt], 0, 0, 0);
    }
  }
}

// ---------------- phi GEMM (MFMA): linxi[pt][c] = Wphi @ featB[pt] + bphi ----------------
__global__ __launch_bounds__(256) void phi_kernel(const u16* __restrict__ featB,
                                                  const u16* __restrict__ WphiB,
                                                  const float* __restrict__ bphi,
                                                  float* __restrict__ linxi)
{
  __shared__ uint4 Xs4[64*16];
  int tid = threadIdx.x, lane = tid & 63, wid = tid >> 6;
  int row = lane & 15, g = lane >> 4, m0 = wid * 32;
  size_t g0 = (size_t)blockIdx.x * 64;
  for (int u = tid; u < 1024; u += 256) {
    int p = u >> 4, seg = u & 15;
    Xs4[p*16 + (seg ^ (p & 7))] = *(const uint4*)&featB[(g0 + p)*128 + seg*8];
  }
  __syncthreads();
  short8 afr[2][4];
  load_af(WphiB, m0, row, g, afr);
  f32x4 acc[2][4];
  zero_acc(acc);
  gemm64(afr, Xs4, row, g, acc);
  #pragma unroll
  for (int mt = 0; mt < 2; ++mt) {
    int c = m0 + mt*16 + g*4;
    float4 bp = *(const float4*)&bphi[c];
    const float* bpp = (const float*)&bp;
    #pragma unroll
    for (int nt = 0; nt < 4; ++nt) {
      int p = nt*16 + row;
      float4 v = make_float4(acc[mt][nt][0]+bpp[0], acc[mt][nt][1]+bpp[1],
                             acc[mt][nt][2]+bpp[2], acc[mt][nt][3]+bpp[3]);
      *(float4*)&linxi[(g0 + p)*128 + c] = v;
    }
  }
}

// ---------------- pos second moments: per-block partials (deterministic) ----------------
__global__ __launch_bounds__(256) void pos_stats(const float* __restrict__ xyz,
                                                 const int* __restrict__ idx,
                                                 double* __restrict__ part)
{
  __shared__ double rd[256];
  int qg = blockIdx.x*256 + threadIdx.x;
  int b = qg >> 12, n = qg & 4095;
  const float* X = xyz + (size_t)b * 12288;
  float qx = X[n], qy = X[4096+n], qz = X[8192+n];
  double l[9] = {0,0,0,0,0,0,0,0,0};
  for (int kk = 0; kk < 16; ++kk) {
    int nb = idx[(size_t)qg*16 + kk];
    float px = qx - X[nb], py = qy - X[4096+nb], pz = qz - X[8192+nb];
    l[0] += px; l[1] += py; l[2] += pz;
    l[3] += (double)px*px; l[4] += (double)px*py; l[5] += (double)px*pz;
    l[6] += (double)py*py; l[7] += (double)py*pz; l[8] += (double)pz*pz;
  }
  for (int j = 0; j < 9; ++j) {
    __syncthreads();
    rd[threadIdx.x] = l[j];
    __syncthreads();
    for (int s = 128; s > 0; s >>= 1) {
      if (threadIdx.x < s) rd[threadIdx.x] += rd[threadIdx.x + s];
      __syncthreads();
    }
    if (threadIdx.x == 0) part[(size_t)blockIdx.x*9 + j] = rd[0];
  }
}

// ---------------- fold theta BN analytically ----------------
__global__ __launch_bounds__(128) void theta_fold(const double* __restrict__ part,
                                                  const float* __restrict__ Wc,
                                                  const float* __restrict__ bc,
                                                  const float* __restrict__ g,
                                                  const float* __restrict__ be,
                                                  float* __restrict__ WdT,
                                                  float* __restrict__ bd)
{
  int c = threadIdx.x;
  double st[9];
  for (int j = 0; j < 9; ++j) {
    double s = 0.0;
    for (int bk = 0; bk < 32; ++bk) s += part[(size_t)bk*9 + j];
    st[j] = s;
  }
  const double cnt = (double)NNPTS;
  double m0 = st[0]/cnt, m1 = st[1]/cnt, m2 = st[2]/cnt;
  double Pxx = st[3]/cnt, Pxy = st[4]/cnt, Pxz = st[5]/cnt;
  double Pyy = st[6]/cnt, Pyz = st[7]/cnt, Pzz = st[8]/cnt;
  double w0 = Wc[c*3], w1 = Wc[c*3+1], w2 = Wc[c*3+2], bb = bc[c];
  double wm = w0*m0 + w1*m1 + w2*m2;
  double mu = wm + bb;
  double quad = w0*(Pxx*w0 + Pxy*w1 + Pxz*w2)
              + w1*(Pxy*w0 + Pyy*w1 + Pyz*w2)
              + w2*(Pxz*w0 + Pyz*w1 + Pzz*w2);
  double Ex2 = quad + 2.0*bb*wm + bb*bb;
  double var = Ex2 - mu*mu;
  double s = (double)g[c] / sqrt(var + 1e-5);
  double t = (double)be[c] - s*mu;
  WdT[0*128+c] = (float)(s*w0);
  WdT[1*128+c] = (float)(s*w1);
  WdT[2*128+c] = (float)(s*w2);
  bd[c] = (float)(s*bb + t);
}

// ---------------- gamma BN stats: stage 1 (64 blocks x 32 rows, double) ----------------
__global__ __launch_bounds__(256) void gamma_part(const float* __restrict__ gs,
                                                  const float* __restrict__ gq,
                                                  double* __restrict__ partS,
                                                  double* __restrict__ partQ)
{
  int c = threadIdx.x & 127;
  int arr = threadIdx.x >> 7;
  int j = blockIdx.x;
  const float* src = arr ? gq : gs;
  double s = 0.0;
  #pragma unroll 8
  for (int bk = j*32; bk < j*32 + 32; ++bk)
    s += src[(size_t)bk*128 + c];
  (arr ? partQ : partS)[(size_t)j*128 + c] = s;
}

// ---------------- gamma BN stats: stage 2 (final fold) ----------------
__global__ __launch_bounds__(128) void gamma_final(const double* __restrict__ partS,
                                                   const double* __restrict__ partQ,
                                                   const float* __restrict__ g,
                                                   const float* __restrict__ be,
                                                   float* __restrict__ s2,
                                                   float* __restrict__ t2v)
{
  int c = threadIdx.x;
  double S = 0.0, Q = 0.0;
  #pragma unroll 8
  for (int j = 0; j < 64; ++j) {
    S += partS[(size_t)j*128 + c];
    Q += partQ[(size_t)j*128 + c];
  }
  const double cnt = (double)NNPTS;
  double m = S/cnt, v = Q/cnt - m*m;
  double s = (double)g[c] / sqrt(v + 1e-5);
  s2[c]  = (float)s;
  t2v[c] = (float)((double)be[c] - s*m);
}

// ---------------- single fused GEMM pass: psi -> rel0 -> alpha(F store) -> fus(g2 store) + stats ----------------
__global__ __launch_bounds__(256) void fused_pass(
    const u16* __restrict__ featB, const float* __restrict__ linxi,
    const int* __restrict__ idx, const float* __restrict__ xyz,
    const u16* __restrict__ WpsiB, const float* __restrict__ bpsi,
    const u16* __restrict__ WfusB, const float* __restrict__ c0,
    const u16* __restrict__ WalphaB, const float* __restrict__ balpha,
    const float* __restrict__ WdT, const float* __restrict__ bd,
    float* __restrict__ g2W, float* __restrict__ FW,
    float* __restrict__ gs, float* __restrict__ gq)
{
  __shared__ uint4 Xs4[64*16];                 // gathered features, bf16 swizzled
  __shared__ u16   Rs[64*128];                 // rel0 bf16, same swizzle
  __shared__ float LxS[4][128];
  __shared__ float posS[3][64];
  __shared__ int   pidx[64];
  __shared__ float redS[128], redQ[128];

  int tid = threadIdx.x, lane = tid & 63, wid = tid >> 6;
  int row = lane & 15, g = lane >> 4;
  int m0 = wid * 32;
  int q0 = blockIdx.x * 4, b = q0 >> 12;
  int n0 = q0 & 4095;
  const float* X = xyz + (size_t)b * 12288;
  size_t gp0 = (size_t)blockIdx.x * 64;

  if (tid < 64) {
    int q = tid >> 4;
    int nb = idx[(size_t)(q0 + q)*16 + (tid & 15)];
    pidx[tid] = nb;
    int nq = n0 + q;
    posS[0][tid] = X[nq]      - X[nb];
    posS[1][tid] = X[4096+nq] - X[4096+nb];
    posS[2][tid] = X[8192+nq] - X[8192+nb];
  }
  for (int u = tid; u < 512; u += 256)
    LxS[u >> 7][u & 127] = linxi[(size_t)q0*128 + u];
  __syncthreads();
  {
    const u16* fb = featB + ((size_t)b << 12) * 128;
    for (int u = tid; u < 1024; u += 256) {
      int p = u >> 4, seg = u & 15;
      Xs4[p*16 + (seg ^ (p & 7))] = *(const uint4*)&fb[(size_t)pidx[p]*128 + seg*8];
    }
  }

  // per-lane channel constants
  float4 bpsV[2], wd0V[2], wd1V[2], wd2V[2], bdV[2], c0V[2], baV[2];
  #pragma unroll
  for (int mt = 0; mt < 2; ++mt) {
    int c = m0 + mt*16 + g*4;
    bpsV[mt] = *(const float4*)&bpsi[c];
    wd0V[mt] = *(const float4*)&WdT[c];
    wd1V[mt] = *(const float4*)&WdT[128 + c];
    wd2V[mt] = *(const float4*)&WdT[256 + c];
    bdV[mt]  = *(const float4*)&bd[c];
    c0V[mt]  = *(const float4*)&c0[c];
    baV[mt]  = *(const float4*)&balpha[c];
  }
  __syncthreads();

  short8 afr[2][4];
  f32x4 acc[2][4];

  // ---- psi GEMM ----
  load_af(WpsiB, m0, row, g, afr);
  zero_acc(acc);
  gemm64(afr, Xs4, row, g, acc);

  // ---- rel0 = lin_xi - (psi+b) + delta  -> Rs (bf16, swizzled) ----
  #pragma unroll
  for (int mt = 0; mt < 2; ++mt) {
    int c = m0 + mt*16 + g*4;
    const float* bps = (const float*)&bpsV[mt];
    const float* w0p = (const float*)&wd0V[mt];
    const float* w1p = (const float*)&wd1V[mt];
    const float* w2p = (const float*)&wd2V[mt];
    const float* bdp = (const float*)&bdV[mt];
    #pragma unroll
    for (int nt = 0; nt < 4; ++nt) {
      int p = nt*16 + row;
      float p0 = posS[0][p], p1 = posS[1][p], p2 = posS[2][p];
      const float* lx = &LxS[nt][c];
      ushort4 wvv;
      u16* wvp = (u16*)&wvv;
      #pragma unroll
      for (int r = 0; r < 4; ++r) {
        float d = fmaf(w2p[r], p2, fmaf(w1p[r], p1, fmaf(w0p[r], p0, bdp[r])));
        d = fmaxf(d, 0.f);
        wvp[r] = f2bf(lx[r] - (acc[mt][nt][r] + bps[r]) + d);
      }
      *(ushort4*)&Rs[p*128 + (c ^ ((p & 7) << 3))] = wvv;
    }
  }

  // ---- alpha GEMM on Xs4 (Rs writes race-free: disjoint LDS region) ----
  load_af(WalphaB, m0, row, g, afr);
  zero_acc(acc);
  gemm64(afr, Xs4, row, g, acc);

  // ---- F = alpha + b + delta -> global f32 ----
  #pragma unroll
  for (int mt = 0; mt < 2; ++mt) {
    int c = m0 + mt*16 + g*4;
    const float* bap = (const float*)&baV[mt];
    const float* w0p = (const float*)&wd0V[mt];
    const float* w1p = (const float*)&wd1V[mt];
    const float* w2p = (const float*)&wd2V[mt];
    const float* bdp = (const float*)&bdV[mt];
    #pragma unroll
    for (int nt = 0; nt < 4; ++nt) {
      int p = nt*16 + row;
      float p0 = posS[0][p], p1 = posS[1][p], p2 = posS[2][p];
      float4 v; float* vv = (float*)&v;
      #pragma unroll
      for (int r = 0; r < 4; ++r) {
        float d = fmaf(w2p[r], p2, fmaf(w1p[r], p1, fmaf(w0p[r], p0, bdp[r])));
        d = fmaxf(d, 0.f);
        vv[r] = acc[mt][nt][r] + bap[r] + d;
      }
      *(float4*)&FW[(gp0 + p)*128 + c] = v;
    }
  }
  __syncthreads();   // Rs writes visible before fus reads

  // ---- fused gamma GEMM on rel0 ----
  load_af(WfusB, m0, row, g, afr);
  zero_acc(acc);
  gemm64(afr, (const uint4*)Rs, row, g, acc);

  // ---- gg = fus + c0 -> global f32, + per-block stats partials ----
  #pragma unroll
  for (int mt = 0; mt < 2; ++mt) {
    int c = m0 + mt*16 + g*4;
    const float* c0p = (const float*)&c0V[mt];
    float sv[4], qv[4];
    #pragma unroll
    for (int r = 0; r < 4; ++r) { sv[r] = 0.f; qv[r] = 0.f; }
    #pragma unroll
    for (int nt = 0; nt < 4; ++nt) {
      int p = nt*16 + row;
      float4 v; float* vv = (float*)&v;
      #pragma unroll
      for (int r = 0; r < 4; ++r) {
        float gg = acc[mt][nt][r] + c0p[r];
        vv[r] = gg;
        sv[r] += gg; qv[r] = fmaf(gg, gg, qv[r]);
      }
      *(float4*)&g2W[(gp0 + p)*128 + c] = v;
    }
    #pragma unroll
    for (int r = 0; r < 4; ++r) {
      #pragma unroll
      for (int d = 1; d < 16; d <<= 1) {
        sv[r] += __shfl_xor(sv[r], d);
        qv[r] += __shfl_xor(qv[r], d);
      }
    }
    if (row == 0) {
      *(float4*)&redS[c] = make_float4(sv[0], sv[1], sv[2], sv[3]);
      *(float4*)&redQ[c] = make_float4(qv[0], qv[1], qv[2], qv[3]);
    }
  }
  __syncthreads();
  if (tid < 128) {
    gs[(size_t)blockIdx.x*128 + tid] = redS[tid];
    gq[(size_t)blockIdx.x*128 + tid] = redQ[tid];
  }
}

// ---------------- streaming epilogue: BN+relu -> softmax over K -> weighted sum ----------------
__global__ __launch_bounds__(256) void out_kernel(const float* __restrict__ g2W,
                                                  const float* __restrict__ FW,
                                                  const float* __restrict__ s2,
                                                  const float* __restrict__ t2v,
                                                  float* __restrict__ out)
{
  int tid = threadIdx.x;
  int c = tid & 127;
  int qg = tid >> 7;                 // 0..1
  int q0 = blockIdx.x * 8;           // 8 queries per block
  float s = s2[c], t = t2v[c];
  #pragma unroll
  for (int qi = 0; qi < 4; ++qi) {
    int q = q0 + qi*2 + qg;
    int b = q >> 12, n = q & 4095;
    size_t base = (size_t)q*2048 + c;   // q*16*128
    float rel[16], Fv[16];
    #pragma unroll
    for (int k = 0; k < 16; ++k) {
      rel[k] = fmaxf(fmaf(s, g2W[base + (size_t)k*128], t), 0.f);
      Fv[k]  = FW[base + (size_t)k*128];
    }
    float m = rel[0];
    #pragma unroll
    for (int k = 1; k < 16; ++k) m = fmaxf(m, rel[k]);
    float se = 0.f, so = 0.f;
    #pragma unroll
    for (int k = 0; k < 16; ++k) {
      float e = expf(rel[k] - m);
      se += e; so = fmaf(e, Fv[k], so);
    }
    out[(((size_t)b*128 + c) << 12) + n] = so / se;
  }
}

extern "C" void kernel_launch(void* const* d_in, const int* in_sizes, int n_in,
                              void* d_out, int out_size, void* d_ws, size_t ws_size,
                              hipStream_t stream)
{
  const float* xyz      = (const float*)d_in[0];
  const float* features = (const float*)d_in[1];
  const float* wt1      = (const float*)d_in[2];
  const float* bt1      = (const float*)d_in[3];
  const float* wt2      = (const float*)d_in[4];
  const float* bt2      = (const float*)d_in[5];
  const float* gth      = (const float*)d_in[6];
  const float* bth      = (const float*)d_in[7];
  const float* wphi     = (const float*)d_in[8];
  const float* bphi     = (const float*)d_in[9];
  const float* wpsi     = (const float*)d_in[10];
  const float* bpsi     = (const float*)d_in[11];
  const float* walpha   = (const float*)d_in[12];
  const float* balpha   = (const float*)d_in[13];
  const float* wg1      = (const float*)d_in[14];
  const float* bg1      = (const float*)d_in[15];
  const float* wg2      = (const float*)d_in[16];
  const float* bg2      = (const float*)d_in[17];
  const float* gga      = (const float*)d_in[18];
  const float* bga      = (const float*)d_in[19];

  char* w = (char*)d_ws;
  size_t off = 0;
  auto take = [&](size_t bytes) -> void* {
    void* p = w + off;
    off = (off + bytes + 255) & ~(size_t)255;
    return p;
  };
  int*    idxW    = (int*)   take((size_t)NQ*16*4);
  u16*    featB   = (u16*)   take((size_t)NQ*128*2);
  float*  linxi   = (float*) take((size_t)NQ*128*4);
  u16*    WphiB   = (u16*)   take(32768);
  u16*    WpsiB   = (u16*)   take(32768);
  u16*    WalphaB = (u16*)   take(32768);
  u16*    WfusB   = (u16*)   take(32768);
  float*  c0      = (float*) take(512);
  float*  Wc      = (float*) take(1536);
  float*  bc      = (float*) take(512);
  float*  WdT     = (float*) take(1536);
  float*  bd      = (float*) take(512);
  double* part    = (double*)take(32*9*8);
  float*  gs      = (float*) take((size_t)2048*128*4);
  float*  gq      = (float*) take((size_t)2048*128*4);
  double* partS   = (double*)take((size_t)64*128*8);
  double* partQ   = (double*)take((size_t)64*128*8);
  float*  s2      = (float*) take(512);
  float*  t2v     = (float*) take(512);
  float*  g2W     = (float*) take((size_t)NNPTS*128*4);
  float*  FW      = (float*) take((size_t)NNPTS*128*4);
  float*  out     = (float*)d_out;

  transpose_feat<<<dim3(64, 2, 2), 256, 0, stream>>>(features, featB);
  prep_weights<<<128, 128, 0, stream>>>(wphi, wpsi, walpha, wg1, wg2, bg1, bg2,
                                        wt1, bt1, wt2, bt2,
                                        WphiB, WpsiB, WalphaB, WfusB, c0, Wc, bc);
  knn_kernel<<<2048, 256, 0, stream>>>(xyz, idxW);
  phi_kernel<<<128, 256, 0, stream>>>(featB, WphiB, bphi, linxi);
  pos_stats<<<32, 256, 0, stream>>>(xyz, idxW, part);
  theta_fold<<<1, 128, 0, stream>>>(part, Wc, bc, gth, bth, WdT, bd);
  fused_pass<<<2048, 256, 0, stream>>>(featB, linxi, idxW, xyz,
      WpsiB, bpsi, WfusB, c0, WalphaB, balpha, WdT, bd, g2W, FW, gs, gq);
  gamma_part<<<64, 256, 0, stream>>>(gs, gq, partS, partQ);
  gamma_final<<<1, 128, 0, stream>>>(partS, partQ, gga, bga, s2, t2v);
  out_kernel<<<1024, 256, 0, stream>>>(g2W, FW, s2, t2v, out);
}